// Round 1
// baseline (1714.216 us; speedup 1.0000x reference)
//
#include <hip/hip_runtime.h>

#define LSEQ 2048
#define DMODEL 1024
#define NHEAD 16
#define HDIM 64

// ---------------------------------------------------------------------------
// Tiled fp32 GEMM: Y = X @ W^T + bias
// X: [M, 1024] row-major. W: [1024, 1024] row-major (row = output feature).
// Both are K-contiguous (NT GEMM). 64x64 tile, BK=16, 256 threads, 4x4/thread.
// HEADSPLIT: store Y[m][n] to [B,H,L,HD] layout instead of flat [M,N].
// ---------------------------------------------------------------------------
template <bool HEADSPLIT>
__device__ __forceinline__ void gemm_body(const float* __restrict__ X,
                                          const float* __restrict__ W,
                                          const float* __restrict__ bias,
                                          float* __restrict__ Y) {
    __shared__ alignas(16) float Xs[16][68];
    __shared__ alignas(16) float Ws[16][68];

    const int tid = threadIdx.x;
    const int tr = tid >> 4;        // 0..15 (row group)
    const int tc = tid & 15;        // 0..15 (col group)
    const int m0 = blockIdx.x * 64;
    const int n0 = blockIdx.y * 64;
    const int lm = tid >> 2;        // 0..63: row loaded by this thread
    const int lk = (tid & 3) << 2;  // 0,4,8,12: k-quad loaded

    float acc[4][4] = {};

    for (int k0 = 0; k0 < DMODEL; k0 += 16) {
        float4 xv = *(const float4*)(X + (size_t)(m0 + lm) * DMODEL + k0 + lk);
        float4 wv = *(const float4*)(W + (size_t)(n0 + lm) * DMODEL + k0 + lk);
        __syncthreads();  // previous iteration's reads complete
        Xs[lk + 0][lm] = xv.x; Xs[lk + 1][lm] = xv.y;
        Xs[lk + 2][lm] = xv.z; Xs[lk + 3][lm] = xv.w;
        Ws[lk + 0][lm] = wv.x; Ws[lk + 1][lm] = wv.y;
        Ws[lk + 2][lm] = wv.z; Ws[lk + 3][lm] = wv.w;
        __syncthreads();
        #pragma unroll
        for (int kk = 0; kk < 16; ++kk) {
            float4 a = *(const float4*)&Xs[kk][tr * 4];
            float4 b = *(const float4*)&Ws[kk][tc * 4];
            float av[4] = {a.x, a.y, a.z, a.w};
            float bv[4] = {b.x, b.y, b.z, b.w};
            #pragma unroll
            for (int i = 0; i < 4; ++i)
                #pragma unroll
                for (int j = 0; j < 4; ++j)
                    acc[i][j] += av[i] * bv[j];
        }
    }

    float4 b4 = *(const float4*)(bias + n0 + tc * 4);
    #pragma unroll
    for (int i = 0; i < 4; ++i) {
        const int m = m0 + tr * 4 + i;
        float4 res;
        res.x = acc[i][0] + b4.x;
        res.y = acc[i][1] + b4.y;
        res.z = acc[i][2] + b4.z;
        res.w = acc[i][3] + b4.w;
        if (HEADSPLIT) {
            const int b = m >> 11;       // m / 2048
            const int l = m & 2047;
            const int h = n0 >> 6;       // whole 64-col tile is one head
            *(float4*)(Y + (((size_t)(b * NHEAD + h) * LSEQ + l) * HDIM) + tc * 4) = res;
        } else {
            *(float4*)(Y + (size_t)m * DMODEL + n0 + tc * 4) = res;
        }
    }
}

__global__ __launch_bounds__(256) void qkv_gemm(
    const float* __restrict__ q, const float* __restrict__ k, const float* __restrict__ v,
    const float* __restrict__ Wq, const float* __restrict__ Wk, const float* __restrict__ Wv,
    const float* __restrict__ bq, const float* __restrict__ bk, const float* __restrict__ bv,
    float* __restrict__ Qp, float* __restrict__ Kp, float* __restrict__ Vp) {
    const float *X, *W, *bias;
    float* Y;
    if (blockIdx.z == 0)      { X = q; W = Wq; bias = bq; Y = Qp; }
    else if (blockIdx.z == 1) { X = k; W = Wk; bias = bk; Y = Kp; }
    else                      { X = v; W = Wv; bias = bv; Y = Vp; }
    gemm_body<true>(X, W, bias, Y);
}

__global__ __launch_bounds__(256) void out_gemm(
    const float* __restrict__ X, const float* __restrict__ Wo,
    const float* __restrict__ bo, float* __restrict__ out) {
    gemm_body<false>(X, Wo, bo, out);
}

// ---------------------------------------------------------------------------
// Flash-style attention, fp32. One block = 64 query rows of one (b,h).
// K/V tiles of 64 staged in LDS; online-softmax state (m,l,alpha) in LDS;
// O accumulator (4 rows x 4 cols of HD per thread) in registers.
// ---------------------------------------------------------------------------
__global__ __launch_bounds__(256) void attn_kernel(
    const float* __restrict__ Qp, const float* __restrict__ Kp,
    const float* __restrict__ Vp, const unsigned char* __restrict__ mask,
    float* __restrict__ AO) {
    __shared__ alignas(16) float Qs[64][68];
    __shared__ alignas(16) float Ks[64][68];
    __shared__ alignas(16) float Vs[64][68];
    __shared__ alignas(16) float Ss[64][68];
    __shared__ float m_s[64], l_s[64], al_s[64], bias_s[64];

    const int tid = threadIdx.x;
    const int tr = tid >> 4, tc = tid & 15;
    const int bh = blockIdx.y;       // 0..31
    const int b  = bh >> 4;
    const int h  = bh & 15;
    const int q0 = blockIdx.x * 64;

    const float* Qg = Qp + ((size_t)bh * LSEQ + q0) * HDIM;
    const float* Kg = Kp + (size_t)bh * LSEQ * HDIM;
    const float* Vg = Vp + (size_t)bh * LSEQ * HDIM;
    const unsigned char* mg = mask + (size_t)b * LSEQ;

    // Load Q tile (64x64 floats = 1024 float4, 4 per thread)
    #pragma unroll
    for (int u = 0; u < 4; ++u) {
        const int fi = tid + u * 256;
        const int row = fi >> 4, c4 = fi & 15;
        float4 val = *(const float4*)(Qg + row * HDIM + c4 * 4);
        *(float4*)&Qs[row][c4 * 4] = val;
    }
    if (tid < 64) { m_s[tid] = -1e30f; l_s[tid] = 0.0f; }

    float4 o4[4] = {{0,0,0,0}, {0,0,0,0}, {0,0,0,0}, {0,0,0,0}};

    for (int kt = 0; kt < LSEQ / 64; ++kt) {
        // Stage K/V tiles through registers
        float4 kreg[4], vreg[4];
        #pragma unroll
        for (int u = 0; u < 4; ++u) {
            const int fi = tid + u * 256;
            const int row = fi >> 4, c4 = fi & 15;
            kreg[u] = *(const float4*)(Kg + (size_t)(kt * 64 + row) * HDIM + c4 * 4);
            vreg[u] = *(const float4*)(Vg + (size_t)(kt * 64 + row) * HDIM + c4 * 4);
        }
        const unsigned char mk = (tid < 64) ? mg[kt * 64 + tid] : 0;
        __syncthreads();  // previous iteration's phase-3 reads done
        #pragma unroll
        for (int u = 0; u < 4; ++u) {
            const int fi = tid + u * 256;
            const int row = fi >> 4, c4 = fi & 15;
            *(float4*)&Ks[row][c4 * 4] = kreg[u];
            *(float4*)&Vs[row][c4 * 4] = vreg[u];
        }
        if (tid < 64) bias_s[tid] = mk ? -1e30f : 0.0f;
        __syncthreads();

        // Phase 1: S = (Q K^T) * scale + mask_bias
        float s[4][4] = {};
        #pragma unroll
        for (int kk = 0; kk < 16; ++kk) {
            float4 aa[4], bb[4];
            #pragma unroll
            for (int i = 0; i < 4; ++i) aa[i] = *(const float4*)&Qs[tr * 4 + i][kk * 4];
            #pragma unroll
            for (int j = 0; j < 4; ++j) bb[j] = *(const float4*)&Ks[tc * 4 + j][kk * 4];
            #pragma unroll
            for (int i = 0; i < 4; ++i)
                #pragma unroll
                for (int j = 0; j < 4; ++j)
                    s[i][j] += aa[i].x * bb[j].x + aa[i].y * bb[j].y +
                               aa[i].z * bb[j].z + aa[i].w * bb[j].w;
        }
        #pragma unroll
        for (int i = 0; i < 4; ++i) {
            float4 r;
            r.x = s[i][0] * 0.125f + bias_s[tc * 4 + 0];
            r.y = s[i][1] * 0.125f + bias_s[tc * 4 + 1];
            r.z = s[i][2] * 0.125f + bias_s[tc * 4 + 2];
            r.w = s[i][3] * 0.125f + bias_s[tc * 4 + 3];
            *(float4*)&Ss[tr * 4 + i][tc * 4] = r;
        }
        __syncthreads();

        // Phase 2: per-row online softmax (64 threads, one row each)
        if (tid < 64) {
            const int r = tid;
            const float mo = m_s[r];
            float mx = mo;
            #pragma unroll
            for (int c4 = 0; c4 < 16; ++c4) {
                float4 x = *(const float4*)&Ss[r][c4 * 4];
                mx = fmaxf(mx, fmaxf(fmaxf(x.x, x.y), fmaxf(x.z, x.w)));
            }
            const float alpha = __expf(mo - mx);
            float sum = 0.0f;
            #pragma unroll
            for (int c4 = 0; c4 < 16; ++c4) {
                float4 x = *(const float4*)&Ss[r][c4 * 4];
                x.x = __expf(x.x - mx); x.y = __expf(x.y - mx);
                x.z = __expf(x.z - mx); x.w = __expf(x.w - mx);
                sum += x.x + x.y + x.z + x.w;
                *(float4*)&Ss[r][c4 * 4] = x;
            }
            m_s[r] = mx;
            l_s[r] = l_s[r] * alpha + sum;
            al_s[r] = alpha;
        }
        __syncthreads();

        // Phase 3: rescale O, then O += P @ V
        #pragma unroll
        for (int i = 0; i < 4; ++i) {
            const float al = al_s[tr * 4 + i];
            o4[i].x *= al; o4[i].y *= al; o4[i].z *= al; o4[i].w *= al;
        }
        #pragma unroll
        for (int c4 = 0; c4 < 16; ++c4) {
            float4 pp[4], vv[4];
            #pragma unroll
            for (int i = 0; i < 4; ++i) pp[i] = *(const float4*)&Ss[tr * 4 + i][c4 * 4];
            #pragma unroll
            for (int j = 0; j < 4; ++j) vv[j] = *(const float4*)&Vs[c4 * 4 + j][tc * 4];
            #pragma unroll
            for (int i = 0; i < 4; ++i) {
                o4[i].x += pp[i].x * vv[0].x + pp[i].y * vv[1].x + pp[i].z * vv[2].x + pp[i].w * vv[3].x;
                o4[i].y += pp[i].x * vv[0].y + pp[i].y * vv[1].y + pp[i].z * vv[2].y + pp[i].w * vv[3].y;
                o4[i].z += pp[i].x * vv[0].z + pp[i].y * vv[1].z + pp[i].z * vv[2].z + pp[i].w * vv[3].z;
                o4[i].w += pp[i].x * vv[0].w + pp[i].y * vv[1].w + pp[i].z * vv[2].w + pp[i].w * vv[3].w;
            }
        }
        __syncthreads();
    }

    // Epilogue: O /= l, store to concat-head layout [B, L, D]
    #pragma unroll
    for (int i = 0; i < 4; ++i) {
        const int r = tr * 4 + i;
        const float inv = 1.0f / l_s[r];
        float4 res;
        res.x = o4[i].x * inv; res.y = o4[i].y * inv;
        res.z = o4[i].z * inv; res.w = o4[i].w * inv;
        const int l = q0 + r;
        *(float4*)(AO + ((size_t)(b * LSEQ + l) * DMODEL) + h * HDIM + tc * 4) = res;
    }
}

extern "C" void kernel_launch(void* const* d_in, const int* in_sizes, int n_in,
                              void* d_out, int out_size, void* d_ws, size_t ws_size,
                              hipStream_t stream) {
    (void)in_sizes; (void)n_in; (void)out_size; (void)ws_size;
    const float* q  = (const float*)d_in[0];
    const float* k  = (const float*)d_in[1];
    const float* v  = (const float*)d_in[2];
    const unsigned char* mask = (const unsigned char*)d_in[3];
    const float* Wq = (const float*)d_in[4];
    const float* bq = (const float*)d_in[5];
    const float* Wk = (const float*)d_in[6];
    const float* bk = (const float*)d_in[7];
    const float* Wv = (const float*)d_in[8];
    const float* bv = (const float*)d_in[9];
    const float* Wo = (const float*)d_in[10];
    const float* bo = (const float*)d_in[11];
    float* out = (float*)d_out;

    float* ws = (float*)d_ws;
    float* Qp = ws;                              // [B,H,L,HD] 16 MiB
    float* Kp = ws + (size_t)4 * 1024 * 1024;    // 16 MiB
    float* Vp = ws + (size_t)8 * 1024 * 1024;    // 16 MiB
    float* AO = ws + (size_t)12 * 1024 * 1024;   // [B,L,D] 16 MiB

    // Q/K/V projections: M=4096, N=1024 -> 64x16 blocks, z in {q,k,v}
    qkv_gemm<<<dim3(64, 16, 3), 256, 0, stream>>>(q, k, v, Wq, Wk, Wv, bq, bk, bv,
                                                  Qp, Kp, Vp);
    // Attention: 32 q-tiles x 32 (b,h) pairs
    attn_kernel<<<dim3(32, 32), 256, 0, stream>>>(Qp, Kp, Vp, mask, AO);
    // Output projection
    out_gemm<<<dim3(64, 16), 256, 0, stream>>>(AO, Wo, bo, out);
}

// Round 2
// 718.280 us; speedup vs baseline: 2.3866x; 2.3866x over previous
//
#include <hip/hip_runtime.h>

#define LSEQ 2048
#define DMODEL 1024
#define NHEAD 16
#define HDIM 64

typedef __attribute__((ext_vector_type(8))) short bf16x8;
typedef __attribute__((ext_vector_type(4))) float f32x4;

static __device__ __forceinline__ unsigned short f2bf(float x) {
    union { float f; unsigned u; } c; c.f = x;
    unsigned r = c.u + 0x7fff + ((c.u >> 16) & 1);  // RNE
    return (unsigned short)(r >> 16);
}

// ---------------------------------------------------------------------------
// Tiled fp32 GEMM: Y = X @ W^T + bias (NT). 64x64 tile, BK=16, 256 thr, 4x4.
// HEADSPLIT: store bf16 to [B,H,L,HD]; else fp32 flat [M,N].
// ---------------------------------------------------------------------------
template <bool HEADSPLIT>
__device__ __forceinline__ void gemm_body(const float* __restrict__ X,
                                          const float* __restrict__ W,
                                          const float* __restrict__ bias,
                                          void* __restrict__ Yv) {
    __shared__ alignas(16) float Xs[16][68];
    __shared__ alignas(16) float Ws[16][68];

    const int tid = threadIdx.x;
    const int tr = tid >> 4;
    const int tc = tid & 15;
    const int m0 = blockIdx.x * 64;
    const int n0 = blockIdx.y * 64;
    const int lm = tid >> 2;
    const int lk = (tid & 3) << 2;

    float acc[4][4] = {};

    for (int k0 = 0; k0 < DMODEL; k0 += 16) {
        float4 xv = *(const float4*)(X + (size_t)(m0 + lm) * DMODEL + k0 + lk);
        float4 wv = *(const float4*)(W + (size_t)(n0 + lm) * DMODEL + k0 + lk);
        __syncthreads();
        Xs[lk + 0][lm] = xv.x; Xs[lk + 1][lm] = xv.y;
        Xs[lk + 2][lm] = xv.z; Xs[lk + 3][lm] = xv.w;
        Ws[lk + 0][lm] = wv.x; Ws[lk + 1][lm] = wv.y;
        Ws[lk + 2][lm] = wv.z; Ws[lk + 3][lm] = wv.w;
        __syncthreads();
        #pragma unroll
        for (int kk = 0; kk < 16; ++kk) {
            float4 a = *(const float4*)&Xs[kk][tr * 4];
            float4 b = *(const float4*)&Ws[kk][tc * 4];
            float av[4] = {a.x, a.y, a.z, a.w};
            float bv[4] = {b.x, b.y, b.z, b.w};
            #pragma unroll
            for (int i = 0; i < 4; ++i)
                #pragma unroll
                for (int j = 0; j < 4; ++j)
                    acc[i][j] += av[i] * bv[j];
        }
    }

    float4 b4 = *(const float4*)(bias + n0 + tc * 4);
    #pragma unroll
    for (int i = 0; i < 4; ++i) {
        const int m = m0 + tr * 4 + i;
        float r0 = acc[i][0] + b4.x, r1 = acc[i][1] + b4.y;
        float r2 = acc[i][2] + b4.z, r3 = acc[i][3] + b4.w;
        if (HEADSPLIT) {
            unsigned short* Y = (unsigned short*)Yv;
            ushort4 r;
            r.x = f2bf(r0); r.y = f2bf(r1); r.z = f2bf(r2); r.w = f2bf(r3);
            const int bb = m >> 11;
            const int l = m & 2047;
            const int h = n0 >> 6;
            *(ushort4*)(Y + (((size_t)(bb * NHEAD + h) * LSEQ + l) * HDIM) + tc * 4) = r;
        } else {
            float* Y = (float*)Yv;
            float4 res = {r0, r1, r2, r3};
            *(float4*)(Y + (size_t)m * DMODEL + n0 + tc * 4) = res;
        }
    }
}

__global__ __launch_bounds__(256) void qkv_gemm(
    const float* __restrict__ q, const float* __restrict__ k, const float* __restrict__ v,
    const float* __restrict__ Wq, const float* __restrict__ Wk, const float* __restrict__ Wv,
    const float* __restrict__ bq, const float* __restrict__ bk, const float* __restrict__ bv,
    unsigned short* __restrict__ Qp, unsigned short* __restrict__ Kp,
    unsigned short* __restrict__ Vp) {
    const float *X, *W, *bias;
    unsigned short* Y;
    if (blockIdx.z == 0)      { X = q; W = Wq; bias = bq; Y = Qp; }
    else if (blockIdx.z == 1) { X = k; W = Wk; bias = bk; Y = Kp; }
    else                      { X = v; W = Wv; bias = bv; Y = Vp; }
    gemm_body<true>(X, W, bias, (void*)Y);
}

__global__ __launch_bounds__(256) void out_gemm(
    const float* __restrict__ X, const float* __restrict__ Wo,
    const float* __restrict__ bo, float* __restrict__ out) {
    gemm_body<false>(X, Wo, bo, (void*)out);
}

// ---------------------------------------------------------------------------
// MFMA flash attention, bf16 inputs / fp32 accum.
// Block = 64 q-rows of one (b,h); 4 waves, wave owns 16 q-rows.
// K staged row-major in LDS (PAD=72 elems -> 144B rows, 16B-aligned).
// V staged TRANSPOSED in LDS so PV B-frags are contiguous b128 reads.
// P round-trips through per-wave LDS (C-layout -> A-layout).
// Softmax state (m,l) per-row in registers, shfl_xor over 16-lane groups.
// ---------------------------------------------------------------------------
#define PAD 72

__global__ __launch_bounds__(256) void attn_mfma(
    const unsigned short* __restrict__ Qp, const unsigned short* __restrict__ Kp,
    const unsigned short* __restrict__ Vp, const unsigned char* __restrict__ mask,
    float* __restrict__ AO) {
    __shared__ alignas(16) unsigned short Ks[64 * PAD];
    __shared__ alignas(16) unsigned short Vts[64 * PAD];
    __shared__ alignas(16) unsigned short Ps[4][16 * PAD];
    __shared__ float bias_s[64];

    const int tid = threadIdx.x;
    const int wave = tid >> 6;
    const int lane = tid & 63;
    const int l16 = lane & 15;
    const int quad = lane >> 4;          // 0..3
    const int bh = blockIdx.y;
    const int b = bh >> 4;
    const int h = bh & 15;
    const int q0 = blockIdx.x * 64 + wave * 16;  // this wave's first global q row

    const unsigned short* Qg = Qp + ((size_t)bh * LSEQ + q0) * HDIM;
    const unsigned short* Kg = Kp + (size_t)bh * LSEQ * HDIM;
    const unsigned short* Vg = Vp + (size_t)bh * LSEQ * HDIM;
    const unsigned char* mg = mask + (size_t)b * LSEQ;

    // Resident Q A-frags: A[m=lane&15][k=quad*8+j], k-chunks 0/1
    bf16x8 qf[2];
    qf[0] = *(const bf16x8*)(Qg + (size_t)l16 * HDIM + quad * 8);
    qf[1] = *(const bf16x8*)(Qg + (size_t)l16 * HDIM + 32 + quad * 8);

    f32x4 o[4];
    #pragma unroll
    for (int nb = 0; nb < 4; ++nb)
        #pragma unroll
        for (int r = 0; r < 4; ++r) o[nb][r] = 0.0f;
    float m_r[4], l_r[4];
    #pragma unroll
    for (int r = 0; r < 4; ++r) { m_r[r] = -1e30f; l_r[r] = 0.0f; }

    // Staging index maps (both l-fast: lane-contiguous LDS banks)
    const int sl0 = tid & 63, sd0 = (tid >> 6) << 3;        // cidx = tid
    const int sl1 = sl0, sd1 = sd0 + 32;                    // cidx = tid + 256

    for (int kt = 0; kt < LSEQ / 64; ++kt) {
        const int k0 = kt * 64;
        // Prefetch K/V tile into registers (overlaps prior tile's MFMA)
        bf16x8 kv0 = *(const bf16x8*)(Kg + (size_t)(k0 + sl0) * HDIM + sd0);
        bf16x8 kv1 = *(const bf16x8*)(Kg + (size_t)(k0 + sl1) * HDIM + sd1);
        bf16x8 vv0 = *(const bf16x8*)(Vg + (size_t)(k0 + sl0) * HDIM + sd0);
        bf16x8 vv1 = *(const bf16x8*)(Vg + (size_t)(k0 + sl1) * HDIM + sd1);
        float bias = 0.0f;
        if (tid < 64) bias = mg[k0 + tid] ? -1e30f : 0.0f;

        __syncthreads();  // prior tile's Ks/Vts reads complete
        *(bf16x8*)(Ks + sl0 * PAD + sd0) = kv0;
        *(bf16x8*)(Ks + sl1 * PAD + sd1) = kv1;
        #pragma unroll
        for (int j = 0; j < 8; ++j) {
            Vts[(sd0 + j) * PAD + sl0] = ((unsigned short)vv0[j]);
            Vts[(sd1 + j) * PAD + sl1] = ((unsigned short)vv1[j]);
        }
        if (tid < 64) bias_s[tid] = bias;
        __syncthreads();

        // ---- S = Q K^T (16q x 64key per wave) ----
        f32x4 s[4];
        #pragma unroll
        for (int kb = 0; kb < 4; ++kb)
            #pragma unroll
            for (int r = 0; r < 4; ++r) s[kb][r] = 0.0f;
        #pragma unroll
        for (int c = 0; c < 2; ++c) {
            #pragma unroll
            for (int kb = 0; kb < 4; ++kb) {
                bf16x8 bfrag = *(const bf16x8*)(Ks + (kb * 16 + l16) * PAD + c * 32 + quad * 8);
                s[kb] = __builtin_amdgcn_mfma_f32_16x16x32_bf16(qf[c], bfrag, s[kb], 0, 0, 0);
            }
        }
        // scale + mask bias (C-layout: row=quad*4+r, col=l16+16*kb)
        #pragma unroll
        for (int kb = 0; kb < 4; ++kb) {
            const float bb = bias_s[kb * 16 + l16];
            #pragma unroll
            for (int r = 0; r < 4; ++r) s[kb][r] = s[kb][r] * 0.125f + bb;
        }

        // ---- online softmax (per-row, reduce over 16 lanes in group) ----
        unsigned short* Pw = &Ps[wave][0];
        #pragma unroll
        for (int r = 0; r < 4; ++r) {
            float mrow = fmaxf(fmaxf(s[0][r], s[1][r]), fmaxf(s[2][r], s[3][r]));
            #pragma unroll
            for (int off = 1; off < 16; off <<= 1)
                mrow = fmaxf(mrow, __shfl_xor(mrow, off, 64));
            const float mnew = fmaxf(m_r[r], mrow);
            const float alpha = __expf(m_r[r] - mnew);
            m_r[r] = mnew;
            float rs = 0.0f;
            #pragma unroll
            for (int kb = 0; kb < 4; ++kb) {
                const float p = __expf(s[kb][r] - mnew);
                s[kb][r] = p;
                rs += p;
            }
            #pragma unroll
            for (int off = 1; off < 16; off <<= 1)
                rs += __shfl_xor(rs, off, 64);
            l_r[r] = l_r[r] * alpha + rs;
            #pragma unroll
            for (int nb = 0; nb < 4; ++nb) o[nb][r] *= alpha;
        }

        // ---- P: C-layout -> LDS -> A-layout (per-wave buffer, no barrier) ----
        #pragma unroll
        for (int kb = 0; kb < 4; ++kb)
            #pragma unroll
            for (int r = 0; r < 4; ++r)
                Pw[(quad * 4 + r) * PAD + kb * 16 + l16] = f2bf(s[kb][r]);
        asm volatile("s_waitcnt lgkmcnt(0)" ::: "memory");

        bf16x8 pf0 = *(const bf16x8*)(Pw + l16 * PAD + quad * 8);
        bf16x8 pf1 = *(const bf16x8*)(Pw + l16 * PAD + 32 + quad * 8);

        // ---- O += P V ----
        #pragma unroll
        for (int nb = 0; nb < 4; ++nb) {
            bf16x8 v0 = *(const bf16x8*)(Vts + (nb * 16 + l16) * PAD + quad * 8);
            o[nb] = __builtin_amdgcn_mfma_f32_16x16x32_bf16(pf0, v0, o[nb], 0, 0, 0);
            bf16x8 v1 = *(const bf16x8*)(Vts + (nb * 16 + l16) * PAD + 32 + quad * 8);
            o[nb] = __builtin_amdgcn_mfma_f32_16x16x32_bf16(pf1, v1, o[nb], 0, 0, 0);
        }
    }

    // Epilogue: O /= l, store fp32 to AO [B, L, D] (concat heads)
    #pragma unroll
    for (int r = 0; r < 4; ++r) {
        const float inv = 1.0f / l_r[r];
        const int row = q0 + quad * 4 + r;
        float* dst = AO + ((size_t)(b * LSEQ + row) * DMODEL) + h * HDIM;
        #pragma unroll
        for (int nb = 0; nb < 4; ++nb)
            dst[nb * 16 + l16] = o[nb][r] * inv;
    }
}

extern "C" void kernel_launch(void* const* d_in, const int* in_sizes, int n_in,
                              void* d_out, int out_size, void* d_ws, size_t ws_size,
                              hipStream_t stream) {
    (void)in_sizes; (void)n_in; (void)out_size; (void)ws_size;
    const float* q  = (const float*)d_in[0];
    const float* k  = (const float*)d_in[1];
    const float* v  = (const float*)d_in[2];
    const unsigned char* mask = (const unsigned char*)d_in[3];
    const float* Wq = (const float*)d_in[4];
    const float* bq = (const float*)d_in[5];
    const float* Wk = (const float*)d_in[6];
    const float* bk = (const float*)d_in[7];
    const float* Wv = (const float*)d_in[8];
    const float* bv = (const float*)d_in[9];
    const float* Wo = (const float*)d_in[10];
    const float* bo = (const float*)d_in[11];
    float* out = (float*)d_out;

    unsigned short* ws16 = (unsigned short*)d_ws;
    unsigned short* Qp = ws16;                              // [B,H,L,HD] bf16, 8 MiB
    unsigned short* Kp = ws16 + (size_t)4 * 1024 * 1024;    // 8 MiB
    unsigned short* Vp = ws16 + (size_t)8 * 1024 * 1024;    // 8 MiB
    float* AO = (float*)(ws16 + (size_t)12 * 1024 * 1024);  // [B,L,D] fp32, 16 MiB

    qkv_gemm<<<dim3(64, 16, 3), 256, 0, stream>>>(q, k, v, Wq, Wk, Wv, bq, bk, bv,
                                                  Qp, Kp, Vp);
    attn_mfma<<<dim3(32, 32), 256, 0, stream>>>(Qp, Kp, Vp, mask, AO);
    out_gemm<<<dim3(64, 16), 256, 0, stream>>>(AO, Wo, bo, out);
}

// Round 3
// 347.265 us; speedup vs baseline: 4.9363x; 2.0684x over previous
//
#include <hip/hip_runtime.h>

#define LSEQ 2048
#define DMODEL 1024
#define NHEAD 16
#define HDIM 64

typedef __attribute__((ext_vector_type(8))) short bf16x8;
typedef __attribute__((ext_vector_type(4))) float f32x4;
typedef unsigned int u32;

static __device__ __forceinline__ unsigned short f2bf(float x) {
    union { float f; unsigned u; } c; c.f = x;
    unsigned r = c.u + 0x7fff + ((c.u >> 16) & 1);  // RNE
    return (unsigned short)(r >> 16);
}

// async global->LDS, 16B per lane. LDS dest must be wave-uniform base + lane*16.
static __device__ __forceinline__ void gll16(const void* g, void* l) {
    __builtin_amdgcn_global_load_lds(
        (const __attribute__((address_space(1))) u32*)g,
        (__attribute__((address_space(3))) u32*)l, 16, 0, 0);
}

// ---------------------------------------------------------------------------
// Weight converter: fp32 [1024,1024] -> bf16, z picks which W.
// ---------------------------------------------------------------------------
__global__ __launch_bounds__(256) void conv_w(
    const float* __restrict__ w0, const float* __restrict__ w1,
    const float* __restrict__ w2, const float* __restrict__ w3,
    unsigned short* __restrict__ o0, unsigned short* __restrict__ o1,
    unsigned short* __restrict__ o2, unsigned short* __restrict__ o3) {
    const float* s; unsigned short* d;
    const int z = blockIdx.y;
    if (z == 0)      { s = w0; d = o0; }
    else if (z == 1) { s = w1; d = o1; }
    else if (z == 2) { s = w2; d = o2; }
    else             { s = w3; d = o3; }
    const int i = (blockIdx.x * 256 + threadIdx.x) * 4;
    float4 v = *(const float4*)(s + i);
    ushort4 r;
    r.x = f2bf(v.x); r.y = f2bf(v.y); r.z = f2bf(v.z); r.w = f2bf(v.w);
    *(ushort4*)(d + i) = r;
}

// ---------------------------------------------------------------------------
// m97-style MFMA GEMM: Y = X @ W^T + bias. 128x128 tile, BK=32, 256 thr,
// 4 waves in 2x2, each wave 64x64 (4x4 MFMAs of 16x16x32).
// MODE 0: X fp32 (convert in staging), Y bf16 head-split [B,H,L,HD].
// MODE 1: X bf16 (global_load_lds), Y fp32 flat [M,N].
// ---------------------------------------------------------------------------
template <int MODE>
__device__ __forceinline__ void mfma_gemm(const void* __restrict__ Xv,
                                          const unsigned short* __restrict__ Wb,
                                          const float* __restrict__ bias,
                                          void* __restrict__ Yv) {
    __shared__ alignas(16) unsigned short As[128 * 32];
    __shared__ alignas(16) unsigned short Bs[128 * 32];

    const int tid = threadIdx.x;
    const int wave = tid >> 6, lane = tid & 63;
    const int l16 = lane & 15, quad = lane >> 4;
    const int wm = (wave >> 1) * 64, wn = (wave & 1) * 64;
    const int m0 = blockIdx.x * 128, n0 = blockIdx.y * 128;

    f32x4 acc[4][4];
    #pragma unroll
    for (int i = 0; i < 4; ++i)
        #pragma unroll
        for (int j = 0; j < 4; ++j)
            #pragma unroll
            for (int r = 0; r < 4; ++r) acc[i][j][r] = 0.0f;

    for (int k0 = 0; k0 < DMODEL; k0 += 32) {
        float4 a0, a1, a2, a3;
        if (MODE == 0) {
            // A: 128 rows x 32 k; thread t handles row t>>1, k-half (t&1)*16
            const float* ag = (const float*)Xv +
                (size_t)(m0 + (tid >> 1)) * DMODEL + k0 + (tid & 1) * 16;
            a0 = *(const float4*)(ag + 0);
            a1 = *(const float4*)(ag + 4);
            a2 = *(const float4*)(ag + 8);
            a3 = *(const float4*)(ag + 12);
        }
        __syncthreads();  // previous step's LDS reads complete
        if (MODE == 0) {
            union { bf16x8 v; unsigned short u[8]; } p0, p1;
            p0.u[0] = f2bf(a0.x); p0.u[1] = f2bf(a0.y);
            p0.u[2] = f2bf(a0.z); p0.u[3] = f2bf(a0.w);
            p0.u[4] = f2bf(a1.x); p0.u[5] = f2bf(a1.y);
            p0.u[6] = f2bf(a1.z); p0.u[7] = f2bf(a1.w);
            p1.u[0] = f2bf(a2.x); p1.u[1] = f2bf(a2.y);
            p1.u[2] = f2bf(a2.z); p1.u[3] = f2bf(a2.w);
            p1.u[4] = f2bf(a3.x); p1.u[5] = f2bf(a3.y);
            p1.u[6] = f2bf(a3.z); p1.u[7] = f2bf(a3.w);
            *(bf16x8*)(As + tid * 16) = p0.v;
            *(bf16x8*)(As + tid * 16 + 8) = p1.v;
        } else {
            const unsigned short* ab = (const unsigned short*)Xv;
            gll16(ab + (size_t)(m0 + (tid >> 2)) * DMODEL + k0 + (tid & 3) * 8,
                  As + tid * 8);
            gll16(ab + (size_t)(m0 + 64 + (tid >> 2)) * DMODEL + k0 + (tid & 3) * 8,
                  As + 2048 + tid * 8);
        }
        gll16(Wb + (size_t)(n0 + (tid >> 2)) * DMODEL + k0 + (tid & 3) * 8,
              Bs + tid * 8);
        gll16(Wb + (size_t)(n0 + 64 + (tid >> 2)) * DMODEL + k0 + (tid & 3) * 8,
              Bs + 2048 + tid * 8);
        __syncthreads();  // staging drained (compiler emits vmcnt/lgkmcnt)

        bf16x8 af[4], bf[4];
        #pragma unroll
        for (int mb = 0; mb < 4; ++mb)
            af[mb] = *(const bf16x8*)(As + (wm + mb * 16 + l16) * 32 + quad * 8);
        #pragma unroll
        for (int nb = 0; nb < 4; ++nb)
            bf[nb] = *(const bf16x8*)(Bs + (wn + nb * 16 + l16) * 32 + quad * 8);
        #pragma unroll
        for (int mb = 0; mb < 4; ++mb)
            #pragma unroll
            for (int nb = 0; nb < 4; ++nb)
                acc[mb][nb] = __builtin_amdgcn_mfma_f32_16x16x32_bf16(
                    af[mb], bf[nb], acc[mb][nb], 0, 0, 0);
    }

    // Epilogue. C-layout: col = l16, row = quad*4 + r.
    #pragma unroll
    for (int nb = 0; nb < 4; ++nb) {
        const int n = n0 + wn + nb * 16 + l16;
        const float bn = bias[n];
        #pragma unroll
        for (int mb = 0; mb < 4; ++mb) {
            #pragma unroll
            for (int r = 0; r < 4; ++r) {
                const int m = m0 + wm + mb * 16 + quad * 4 + r;
                const float val = acc[mb][nb][r] + bn;
                if (MODE == 0) {
                    unsigned short* Y = (unsigned short*)Yv;
                    const int b = m >> 11, l = m & 2047;
                    const int h = n >> 6, hd = n & 63;
                    Y[(((size_t)(b * NHEAD + h) * LSEQ + l) * HDIM) + hd] = f2bf(val);
                } else {
                    float* Y = (float*)Yv;
                    Y[(size_t)m * DMODEL + n] = val;
                }
            }
        }
    }
}

__global__ __launch_bounds__(256) void qkv_gemm(
    const float* __restrict__ q, const float* __restrict__ k, const float* __restrict__ v,
    const unsigned short* __restrict__ Wqb, const unsigned short* __restrict__ Wkb,
    const unsigned short* __restrict__ Wvb,
    const float* __restrict__ bq, const float* __restrict__ bk, const float* __restrict__ bv,
    unsigned short* __restrict__ Qp, unsigned short* __restrict__ Kp,
    unsigned short* __restrict__ Vp) {
    const float* X; const unsigned short* W; const float* bias; unsigned short* Y;
    if (blockIdx.z == 0)      { X = q; W = Wqb; bias = bq; Y = Qp; }
    else if (blockIdx.z == 1) { X = k; W = Wkb; bias = bk; Y = Kp; }
    else                      { X = v; W = Wvb; bias = bv; Y = Vp; }
    mfma_gemm<0>((const void*)X, W, bias, (void*)Y);
}

__global__ __launch_bounds__(256) void out_gemm(
    const unsigned short* __restrict__ AOb, const unsigned short* __restrict__ Wob,
    const float* __restrict__ bo, float* __restrict__ out) {
    mfma_gemm<1>((const void*)AOb, Wob, bo, (void*)out);
}

// ---------------------------------------------------------------------------
// MFMA flash attention (unchanged except bf16 AO store).
// ---------------------------------------------------------------------------
#define PAD 72

__global__ __launch_bounds__(256) void attn_mfma(
    const unsigned short* __restrict__ Qp, const unsigned short* __restrict__ Kp,
    const unsigned short* __restrict__ Vp, const unsigned char* __restrict__ mask,
    unsigned short* __restrict__ AOb) {
    __shared__ alignas(16) unsigned short Ks[64 * PAD];
    __shared__ alignas(16) unsigned short Vts[64 * PAD];
    __shared__ alignas(16) unsigned short Ps[4][16 * PAD];
    __shared__ float bias_s[64];

    const int tid = threadIdx.x;
    const int wave = tid >> 6;
    const int lane = tid & 63;
    const int l16 = lane & 15;
    const int quad = lane >> 4;
    const int bh = blockIdx.y;
    const int b = bh >> 4;
    const int h = bh & 15;
    const int q0 = blockIdx.x * 64 + wave * 16;

    const unsigned short* Qg = Qp + ((size_t)bh * LSEQ + q0) * HDIM;
    const unsigned short* Kg = Kp + (size_t)bh * LSEQ * HDIM;
    const unsigned short* Vg = Vp + (size_t)bh * LSEQ * HDIM;
    const unsigned char* mg = mask + (size_t)b * LSEQ;

    bf16x8 qf[2];
    qf[0] = *(const bf16x8*)(Qg + (size_t)l16 * HDIM + quad * 8);
    qf[1] = *(const bf16x8*)(Qg + (size_t)l16 * HDIM + 32 + quad * 8);

    f32x4 o[4];
    #pragma unroll
    for (int nb = 0; nb < 4; ++nb)
        #pragma unroll
        for (int r = 0; r < 4; ++r) o[nb][r] = 0.0f;
    float m_r[4], l_r[4];
    #pragma unroll
    for (int r = 0; r < 4; ++r) { m_r[r] = -1e30f; l_r[r] = 0.0f; }

    const int sl0 = tid & 63, sd0 = (tid >> 6) << 3;
    const int sl1 = sl0, sd1 = sd0 + 32;

    for (int kt = 0; kt < LSEQ / 64; ++kt) {
        const int k0 = kt * 64;
        bf16x8 kv0 = *(const bf16x8*)(Kg + (size_t)(k0 + sl0) * HDIM + sd0);
        bf16x8 kv1 = *(const bf16x8*)(Kg + (size_t)(k0 + sl1) * HDIM + sd1);
        bf16x8 vv0 = *(const bf16x8*)(Vg + (size_t)(k0 + sl0) * HDIM + sd0);
        bf16x8 vv1 = *(const bf16x8*)(Vg + (size_t)(k0 + sl1) * HDIM + sd1);
        float bias = 0.0f;
        if (tid < 64) bias = mg[k0 + tid] ? -1e30f : 0.0f;

        __syncthreads();
        *(bf16x8*)(Ks + sl0 * PAD + sd0) = kv0;
        *(bf16x8*)(Ks + sl1 * PAD + sd1) = kv1;
        #pragma unroll
        for (int j = 0; j < 8; ++j) {
            Vts[(sd0 + j) * PAD + sl0] = ((unsigned short)vv0[j]);
            Vts[(sd1 + j) * PAD + sl1] = ((unsigned short)vv1[j]);
        }
        if (tid < 64) bias_s[tid] = bias;
        __syncthreads();

        f32x4 s[4];
        #pragma unroll
        for (int kb = 0; kb < 4; ++kb)
            #pragma unroll
            for (int r = 0; r < 4; ++r) s[kb][r] = 0.0f;
        #pragma unroll
        for (int c = 0; c < 2; ++c) {
            #pragma unroll
            for (int kb = 0; kb < 4; ++kb) {
                bf16x8 bfrag = *(const bf16x8*)(Ks + (kb * 16 + l16) * PAD + c * 32 + quad * 8);
                s[kb] = __builtin_amdgcn_mfma_f32_16x16x32_bf16(qf[c], bfrag, s[kb], 0, 0, 0);
            }
        }
        #pragma unroll
        for (int kb = 0; kb < 4; ++kb) {
            const float bb = bias_s[kb * 16 + l16];
            #pragma unroll
            for (int r = 0; r < 4; ++r) s[kb][r] = s[kb][r] * 0.125f + bb;
        }

        unsigned short* Pw = &Ps[wave][0];
        #pragma unroll
        for (int r = 0; r < 4; ++r) {
            float mrow = fmaxf(fmaxf(s[0][r], s[1][r]), fmaxf(s[2][r], s[3][r]));
            #pragma unroll
            for (int off = 1; off < 16; off <<= 1)
                mrow = fmaxf(mrow, __shfl_xor(mrow, off, 64));
            const float mnew = fmaxf(m_r[r], mrow);
            const float alpha = __expf(m_r[r] - mnew);
            m_r[r] = mnew;
            float rs = 0.0f;
            #pragma unroll
            for (int kb = 0; kb < 4; ++kb) {
                const float p = __expf(s[kb][r] - mnew);
                s[kb][r] = p;
                rs += p;
            }
            #pragma unroll
            for (int off = 1; off < 16; off <<= 1)
                rs += __shfl_xor(rs, off, 64);
            l_r[r] = l_r[r] * alpha + rs;
            #pragma unroll
            for (int nb = 0; nb < 4; ++nb) o[nb][r] *= alpha;
        }

        #pragma unroll
        for (int kb = 0; kb < 4; ++kb)
            #pragma unroll
            for (int r = 0; r < 4; ++r)
                Pw[(quad * 4 + r) * PAD + kb * 16 + l16] = f2bf(s[kb][r]);
        asm volatile("s_waitcnt lgkmcnt(0)" ::: "memory");

        bf16x8 pf0 = *(const bf16x8*)(Pw + l16 * PAD + quad * 8);
        bf16x8 pf1 = *(const bf16x8*)(Pw + l16 * PAD + 32 + quad * 8);

        #pragma unroll
        for (int nb = 0; nb < 4; ++nb) {
            bf16x8 v0 = *(const bf16x8*)(Vts + (nb * 16 + l16) * PAD + quad * 8);
            o[nb] = __builtin_amdgcn_mfma_f32_16x16x32_bf16(pf0, v0, o[nb], 0, 0, 0);
            bf16x8 v1 = *(const bf16x8*)(Vts + (nb * 16 + l16) * PAD + 32 + quad * 8);
            o[nb] = __builtin_amdgcn_mfma_f32_16x16x32_bf16(pf1, v1, o[nb], 0, 0, 0);
        }
    }

    #pragma unroll
    for (int r = 0; r < 4; ++r) {
        const float inv = 1.0f / l_r[r];
        const int row = q0 + quad * 4 + r;
        unsigned short* dst = AOb + ((size_t)(b * LSEQ + row) * DMODEL) + h * HDIM;
        #pragma unroll
        for (int nb = 0; nb < 4; ++nb)
            dst[nb * 16 + l16] = f2bf(o[nb][r] * inv);
    }
}

extern "C" void kernel_launch(void* const* d_in, const int* in_sizes, int n_in,
                              void* d_out, int out_size, void* d_ws, size_t ws_size,
                              hipStream_t stream) {
    (void)in_sizes; (void)n_in; (void)out_size; (void)ws_size;
    const float* q  = (const float*)d_in[0];
    const float* k  = (const float*)d_in[1];
    const float* v  = (const float*)d_in[2];
    const unsigned char* mask = (const unsigned char*)d_in[3];
    const float* Wq = (const float*)d_in[4];
    const float* bq = (const float*)d_in[5];
    const float* Wk = (const float*)d_in[6];
    const float* bk = (const float*)d_in[7];
    const float* Wv = (const float*)d_in[8];
    const float* bv = (const float*)d_in[9];
    const float* Wo = (const float*)d_in[10];
    const float* bo = (const float*)d_in[11];
    float* out = (float*)d_out;

    unsigned short* ws16 = (unsigned short*)d_ws;
    const size_t M4 = (size_t)4 * 1024 * 1024;
    const size_t M1 = (size_t)1024 * 1024;
    unsigned short* Qp  = ws16;            // [B,H,L,HD] bf16, 8 MiB
    unsigned short* Kp  = ws16 + M4;       // 8 MiB
    unsigned short* Vp  = ws16 + 2 * M4;   // 8 MiB
    unsigned short* AOb = ws16 + 3 * M4;   // [B,L,D] bf16, 8 MiB
    unsigned short* Wqb = ws16 + 4 * M4;           // 2 MiB
    unsigned short* Wkb = ws16 + 4 * M4 + M1;      // 2 MiB
    unsigned short* Wvb = ws16 + 4 * M4 + 2 * M1;  // 2 MiB
    unsigned short* Wob = ws16 + 4 * M4 + 3 * M1;  // 2 MiB

    conv_w<<<dim3(1024, 4), 256, 0, stream>>>(Wq, Wk, Wv, Wo, Wqb, Wkb, Wvb, Wob);
    qkv_gemm<<<dim3(32, 8, 3), 256, 0, stream>>>(q, k, v, Wqb, Wkb, Wvb,
                                                 bq, bk, bv, Qp, Kp, Vp);
    attn_mfma<<<dim3(32, 32), 256, 0, stream>>>(Qp, Kp, Vp, mask, AOb);
    out_gemm<<<dim3(32, 8), 256, 0, stream>>>(AOb, Wob, bo, out);
}

// Round 4
// 308.703 us; speedup vs baseline: 5.5530x; 1.1249x over previous
//
#include <hip/hip_runtime.h>

#define LSEQ 2048
#define DMODEL 1024
#define NHEAD 16
#define HDIM 64

typedef __attribute__((ext_vector_type(8))) short bf16x8;
typedef __attribute__((ext_vector_type(4))) float f32x4;
typedef unsigned int u32;
typedef unsigned short u16;

static __device__ __forceinline__ u16 f2bf(float x) {
    union { float f; unsigned u; } c; c.f = x;
    unsigned r = c.u + 0x7fff + ((c.u >> 16) & 1);  // RNE
    return (u16)(r >> 16);
}

// async global->LDS, 16B per lane. LDS dest must be wave-uniform base + lane*16.
static __device__ __forceinline__ void gll16(const void* g, void* l) {
    __builtin_amdgcn_global_load_lds(
        (const __attribute__((address_space(1))) u32*)g,
        (__attribute__((address_space(3))) u32*)l, 16, 0, 0);
}

// 16-lane (DPP row) max butterfly on the VALU pipe — no LDS traffic.
static __device__ __forceinline__ float rowmax16(float x) {
    int t;
    t = __builtin_amdgcn_update_dpp(0, __builtin_bit_cast(int, x), 0x128, 0xf, 0xf, true); // row_ror:8
    x = fmaxf(x, __builtin_bit_cast(float, t));
    t = __builtin_amdgcn_update_dpp(0, __builtin_bit_cast(int, x), 0x124, 0xf, 0xf, true); // row_ror:4
    x = fmaxf(x, __builtin_bit_cast(float, t));
    t = __builtin_amdgcn_update_dpp(0, __builtin_bit_cast(int, x), 0x122, 0xf, 0xf, true); // row_ror:2
    x = fmaxf(x, __builtin_bit_cast(float, t));
    t = __builtin_amdgcn_update_dpp(0, __builtin_bit_cast(int, x), 0x121, 0xf, 0xf, true); // row_ror:1
    x = fmaxf(x, __builtin_bit_cast(float, t));
    return x;
}

// ---------------------------------------------------------------------------
// Weight converter: fp32 [1024,1024] -> bf16, y picks which W.
// ---------------------------------------------------------------------------
__global__ __launch_bounds__(256) void conv_w(
    const float* __restrict__ w0, const float* __restrict__ w1,
    const float* __restrict__ w2, const float* __restrict__ w3,
    u16* __restrict__ o0, u16* __restrict__ o1,
    u16* __restrict__ o2, u16* __restrict__ o3) {
    const float* s; u16* d;
    const int z = blockIdx.y;
    if (z == 0)      { s = w0; d = o0; }
    else if (z == 1) { s = w1; d = o1; }
    else if (z == 2) { s = w2; d = o2; }
    else             { s = w3; d = o3; }
    const int i = (blockIdx.x * 256 + threadIdx.x) * 4;
    float4 v = *(const float4*)(s + i);
    ushort4 r;
    r.x = f2bf(v.x); r.y = f2bf(v.y); r.z = f2bf(v.z); r.w = f2bf(v.w);
    *(ushort4*)(d + i) = r;
}

// ---------------------------------------------------------------------------
// m97-style MFMA GEMM: Y = X @ W^T + bias. 128x128 tile, BK=32, 256 thr.
// IN_MODE 0: X fp32 (convert during staging). IN_MODE 1: X bf16 (gll16).
// OUT_MODE 0: bf16 head-split [B,H,L,HD]. 1: fp32 flat [M,N].
//          2: bf16 head-split TRANSPOSED [B,H,HD,L] (for V).
// ---------------------------------------------------------------------------
template <int IN_MODE, int OUT_MODE>
__device__ __forceinline__ void mfma_gemm(const void* __restrict__ Xv,
                                          const u16* __restrict__ Wb,
                                          const float* __restrict__ bias,
                                          void* __restrict__ Yv) {
    __shared__ alignas(16) u16 As[128 * 32];
    __shared__ alignas(16) u16 Bs[128 * 32];

    const int tid = threadIdx.x;
    const int wave = tid >> 6, lane = tid & 63;
    const int l16 = lane & 15, quad = lane >> 4;
    const int wm = (wave >> 1) * 64, wn = (wave & 1) * 64;
    const int m0 = blockIdx.x * 128, n0 = blockIdx.y * 128;

    f32x4 acc[4][4];
    #pragma unroll
    for (int i = 0; i < 4; ++i)
        #pragma unroll
        for (int j = 0; j < 4; ++j)
            #pragma unroll
            for (int r = 0; r < 4; ++r) acc[i][j][r] = 0.0f;

    for (int k0 = 0; k0 < DMODEL; k0 += 32) {
        float4 a0, a1, a2, a3;
        if (IN_MODE == 0) {
            const float* ag = (const float*)Xv +
                (size_t)(m0 + (tid >> 1)) * DMODEL + k0 + (tid & 1) * 16;
            a0 = *(const float4*)(ag + 0);
            a1 = *(const float4*)(ag + 4);
            a2 = *(const float4*)(ag + 8);
            a3 = *(const float4*)(ag + 12);
        }
        __syncthreads();
        if (IN_MODE == 0) {
            union { bf16x8 v; u16 u[8]; } p0, p1;
            p0.u[0] = f2bf(a0.x); p0.u[1] = f2bf(a0.y);
            p0.u[2] = f2bf(a0.z); p0.u[3] = f2bf(a0.w);
            p0.u[4] = f2bf(a1.x); p0.u[5] = f2bf(a1.y);
            p0.u[6] = f2bf(a1.z); p0.u[7] = f2bf(a1.w);
            p1.u[0] = f2bf(a2.x); p1.u[1] = f2bf(a2.y);
            p1.u[2] = f2bf(a2.z); p1.u[3] = f2bf(a2.w);
            p1.u[4] = f2bf(a3.x); p1.u[5] = f2bf(a3.y);
            p1.u[6] = f2bf(a3.z); p1.u[7] = f2bf(a3.w);
            *(bf16x8*)(As + tid * 16) = p0.v;
            *(bf16x8*)(As + tid * 16 + 8) = p1.v;
        } else {
            const u16* ab = (const u16*)Xv;
            gll16(ab + (size_t)(m0 + (tid >> 2)) * DMODEL + k0 + (tid & 3) * 8,
                  As + tid * 8);
            gll16(ab + (size_t)(m0 + 64 + (tid >> 2)) * DMODEL + k0 + (tid & 3) * 8,
                  As + 2048 + tid * 8);
        }
        gll16(Wb + (size_t)(n0 + (tid >> 2)) * DMODEL + k0 + (tid & 3) * 8,
              Bs + tid * 8);
        gll16(Wb + (size_t)(n0 + 64 + (tid >> 2)) * DMODEL + k0 + (tid & 3) * 8,
              Bs + 2048 + tid * 8);
        __syncthreads();

        bf16x8 af[4], bf[4];
        #pragma unroll
        for (int mb = 0; mb < 4; ++mb)
            af[mb] = *(const bf16x8*)(As + (wm + mb * 16 + l16) * 32 + quad * 8);
        #pragma unroll
        for (int nb = 0; nb < 4; ++nb)
            bf[nb] = *(const bf16x8*)(Bs + (wn + nb * 16 + l16) * 32 + quad * 8);
        #pragma unroll
        for (int mb = 0; mb < 4; ++mb)
            #pragma unroll
            for (int nb = 0; nb < 4; ++nb)
                acc[mb][nb] = __builtin_amdgcn_mfma_f32_16x16x32_bf16(
                    af[mb], bf[nb], acc[mb][nb], 0, 0, 0);
    }

    // Epilogue. C-layout: col = l16, row = quad*4 + r.
    #pragma unroll
    for (int nb = 0; nb < 4; ++nb) {
        const int n = n0 + wn + nb * 16 + l16;
        const float bn = bias[n];
        #pragma unroll
        for (int mb = 0; mb < 4; ++mb) {
            const int mb0 = m0 + wm + mb * 16 + quad * 4;
            if (OUT_MODE == 2) {
                // V^T store: [b,h,hd,l]; 4 r-values = 4 consecutive l.
                u16* Y = (u16*)Yv;
                ushort4 rr;
                rr.x = f2bf(acc[mb][nb][0] + bn);
                rr.y = f2bf(acc[mb][nb][1] + bn);
                rr.z = f2bf(acc[mb][nb][2] + bn);
                rr.w = f2bf(acc[mb][nb][3] + bn);
                const int bb = mb0 >> 11, l = mb0 & 2047;
                const int h = n >> 6, hd = n & 63;
                *(ushort4*)(Y + ((size_t)((bb * NHEAD + h) * HDIM) + hd) * LSEQ + l) = rr;
            } else {
                #pragma unroll
                for (int r = 0; r < 4; ++r) {
                    const int m = mb0 + r;
                    const float val = acc[mb][nb][r] + bn;
                    if (OUT_MODE == 0) {
                        u16* Y = (u16*)Yv;
                        const int bb = m >> 11, l = m & 2047;
                        const int h = n >> 6, hd = n & 63;
                        Y[(((size_t)(bb * NHEAD + h) * LSEQ + l) * HDIM) + hd] = f2bf(val);
                    } else {
                        float* Y = (float*)Yv;
                        Y[(size_t)m * DMODEL + n] = val;
                    }
                }
            }
        }
    }
}

__global__ __launch_bounds__(256) void qkv_gemm(
    const float* __restrict__ q, const float* __restrict__ k, const float* __restrict__ v,
    const u16* __restrict__ Wqb, const u16* __restrict__ Wkb, const u16* __restrict__ Wvb,
    const float* __restrict__ bq, const float* __restrict__ bk, const float* __restrict__ bv,
    u16* __restrict__ Qp, u16* __restrict__ Kp, u16* __restrict__ Vtp) {
    if (blockIdx.z == 0)      mfma_gemm<0, 0>((const void*)q, Wqb, bq, (void*)Qp);
    else if (blockIdx.z == 1) mfma_gemm<0, 0>((const void*)k, Wkb, bk, (void*)Kp);
    else                      mfma_gemm<0, 2>((const void*)v, Wvb, bv, (void*)Vtp);
}

__global__ __launch_bounds__(256) void out_gemm(
    const u16* __restrict__ AOb, const u16* __restrict__ Wob,
    const float* __restrict__ bo, float* __restrict__ out) {
    mfma_gemm<1, 1>((const void*)AOb, Wob, bo, (void*)out);
}

// ---------------------------------------------------------------------------
// MFMA flash attention v2. Block = 128 q-rows of one (b,h); 4 waves; each
// wave owns 32 q-rows as two 16-row groups. K [key][d] and V^T [d][key]
// staged in LDS (stride PAD, b128 in/out). Softmax row-max via DPP butterfly
// (VALU pipe); row-sum AND running l via an extra ones-column MFMA (l obeys
// the same alpha recurrence as O's columns). P round-trips per-wave LDS.
// ---------------------------------------------------------------------------
#define PAD 72

__global__ __launch_bounds__(256) void attn_mfma(
    const u16* __restrict__ Qp, const u16* __restrict__ Kp,
    const u16* __restrict__ Vtp, const unsigned char* __restrict__ mask,
    u16* __restrict__ AOb) {
    __shared__ alignas(16) u16 Ks[64 * PAD];
    __shared__ alignas(16) u16 Vts[64 * PAD];
    __shared__ alignas(16) u16 Ps[8][16 * PAD];
    __shared__ float bias_s[64];

    const int tid = threadIdx.x;
    const int wave = tid >> 6;
    const int lane = tid & 63;
    const int l16 = lane & 15;
    const int quad = lane >> 4;
    const int bh = blockIdx.y;
    const int b = bh >> 4;
    const int h = bh & 15;
    const int q0w = blockIdx.x * 128 + wave * 32;

    const u16* Qg = Qp + ((size_t)bh * LSEQ + q0w) * HDIM;
    const u16* Kg = Kp + (size_t)bh * LSEQ * HDIM;
    const u16* Vtg = Vtp + (size_t)bh * HDIM * LSEQ;
    const unsigned char* mg = mask + (size_t)b * LSEQ;

    // Resident Q A-frags for both 16-row groups
    bf16x8 qf[2][2];
    #pragma unroll
    for (int g = 0; g < 2; ++g)
        #pragma unroll
        for (int c = 0; c < 2; ++c)
            qf[g][c] = *(const bf16x8*)(Qg + (size_t)(g * 16 + l16) * HDIM + c * 32 + quad * 8);

    f32x4 o[2][4], ol[2];
    float m_r[2][4];
    #pragma unroll
    for (int g = 0; g < 2; ++g) {
        #pragma unroll
        for (int nb = 0; nb < 4; ++nb)
            #pragma unroll
            for (int r = 0; r < 4; ++r) o[g][nb][r] = 0.0f;
        #pragma unroll
        for (int r = 0; r < 4; ++r) { ol[g][r] = 0.0f; m_r[g][r] = -1e30f; }
    }

    union { bf16x8 v; u16 u[8]; } ones_u;
    #pragma unroll
    for (int j = 0; j < 8; ++j) ones_u.u[j] = 0x3F80;  // bf16 1.0
    const bf16x8 ones = ones_u.v;

    const int srow = tid >> 3;          // 0..31
    const int sch = (tid & 7) * 8;      // u16 offset of 16B chunk

    for (int kt = 0; kt < LSEQ / 64; ++kt) {
        const int k0 = kt * 64;
        // Prefetch K tile [key][d] and V^T tile [d][key] (coalesced b128)
        bf16x8 kr0 = *(const bf16x8*)(Kg + (size_t)(k0 + srow) * HDIM + sch);
        bf16x8 kr1 = *(const bf16x8*)(Kg + (size_t)(k0 + srow + 32) * HDIM + sch);
        bf16x8 vr0 = *(const bf16x8*)(Vtg + (size_t)srow * LSEQ + k0 + sch);
        bf16x8 vr1 = *(const bf16x8*)(Vtg + (size_t)(srow + 32) * LSEQ + k0 + sch);
        float bias = 0.0f;
        if (tid < 64) bias = mg[k0 + tid] ? -1e30f : 0.0f;

        __syncthreads();  // prior iteration's LDS reads complete
        *(bf16x8*)(Ks + srow * PAD + sch) = kr0;
        *(bf16x8*)(Ks + (srow + 32) * PAD + sch) = kr1;
        *(bf16x8*)(Vts + srow * PAD + sch) = vr0;
        *(bf16x8*)(Vts + (srow + 32) * PAD + sch) = vr1;
        if (tid < 64) bias_s[tid] = bias;
        __syncthreads();

        // K B-frags: read once, reuse for both q-groups
        bf16x8 kf[2][4];
        #pragma unroll
        for (int c = 0; c < 2; ++c)
            #pragma unroll
            for (int kb = 0; kb < 4; ++kb)
                kf[c][kb] = *(const bf16x8*)(Ks + (kb * 16 + l16) * PAD + c * 32 + quad * 8);

        #pragma unroll
        for (int g = 0; g < 2; ++g) {
            // S = Q K^T (32q x 64k per wave, this group's 16 rows)
            f32x4 s[4];
            #pragma unroll
            for (int kb = 0; kb < 4; ++kb)
                #pragma unroll
                for (int r = 0; r < 4; ++r) s[kb][r] = 0.0f;
            #pragma unroll
            for (int c = 0; c < 2; ++c)
                #pragma unroll
                for (int kb = 0; kb < 4; ++kb)
                    s[kb] = __builtin_amdgcn_mfma_f32_16x16x32_bf16(
                        qf[g][c], kf[c][kb], s[kb], 0, 0, 0);
            // scale + mask bias (C-layout: row=quad*4+r, col=l16+16*kb)
            #pragma unroll
            for (int kb = 0; kb < 4; ++kb) {
                const float bb = bias_s[kb * 16 + l16];
                #pragma unroll
                for (int r = 0; r < 4; ++r) s[kb][r] = s[kb][r] * 0.125f + bb;
            }
            // online softmax: DPP row-max; sum deferred to ones-MFMA
            u16* Pw = &Ps[wave * 2 + g][0];
            #pragma unroll
            for (int r = 0; r < 4; ++r) {
                float mx = fmaxf(fmaxf(s[0][r], s[1][r]), fmaxf(s[2][r], s[3][r]));
                mx = rowmax16(mx);
                const float mnew = fmaxf(m_r[g][r], mx);
                const float alpha = __expf(m_r[g][r] - mnew);
                m_r[g][r] = mnew;
                #pragma unroll
                for (int kb = 0; kb < 4; ++kb)
                    s[kb][r] = __expf(s[kb][r] - mnew);
                ol[g][r] *= alpha;
                #pragma unroll
                for (int nb = 0; nb < 4; ++nb) o[g][nb][r] *= alpha;
            }
            // P: C-layout -> per-wave LDS buffer
            #pragma unroll
            for (int kb = 0; kb < 4; ++kb)
                #pragma unroll
                for (int r = 0; r < 4; ++r)
                    Pw[(quad * 4 + r) * PAD + kb * 16 + l16] = f2bf(s[kb][r]);
        }
        asm volatile("s_waitcnt lgkmcnt(0)" ::: "memory");

        // P A-frags + V^T B-frags (V-frags reused across groups)
        bf16x8 pf[2][2];
        #pragma unroll
        for (int g = 0; g < 2; ++g)
            #pragma unroll
            for (int c = 0; c < 2; ++c)
                pf[g][c] = *(const bf16x8*)(&Ps[wave * 2 + g][0] + l16 * PAD + c * 32 + quad * 8);
        bf16x8 vf[2][4];
        #pragma unroll
        for (int c = 0; c < 2; ++c)
            #pragma unroll
            for (int nb = 0; nb < 4; ++nb)
                vf[c][nb] = *(const bf16x8*)(Vts + (nb * 16 + l16) * PAD + c * 32 + quad * 8);

        #pragma unroll
        for (int g = 0; g < 2; ++g) {
            #pragma unroll
            for (int nb = 0; nb < 4; ++nb) {
                o[g][nb] = __builtin_amdgcn_mfma_f32_16x16x32_bf16(pf[g][0], vf[0][nb], o[g][nb], 0, 0, 0);
                o[g][nb] = __builtin_amdgcn_mfma_f32_16x16x32_bf16(pf[g][1], vf[1][nb], o[g][nb], 0, 0, 0);
            }
            // running l: ol += P . ones  (same recurrence as O columns)
            ol[g] = __builtin_amdgcn_mfma_f32_16x16x32_bf16(pf[g][0], ones, ol[g], 0, 0, 0);
            ol[g] = __builtin_amdgcn_mfma_f32_16x16x32_bf16(pf[g][1], ones, ol[g], 0, 0, 0);
        }
    }

    // Epilogue: O /= l, store bf16 to AOb [B, L, D] (concat heads)
    #pragma unroll
    for (int g = 0; g < 2; ++g)
        #pragma unroll
        for (int r = 0; r < 4; ++r) {
            const float inv = 1.0f / ol[g][r];
            const int row = q0w + g * 16 + quad * 4 + r;
            u16* dst = AOb + ((size_t)(b * LSEQ + row) * DMODEL) + h * HDIM;
            #pragma unroll
            for (int nb = 0; nb < 4; ++nb)
                dst[nb * 16 + l16] = f2bf(o[g][nb][r] * inv);
        }
}

extern "C" void kernel_launch(void* const* d_in, const int* in_sizes, int n_in,
                              void* d_out, int out_size, void* d_ws, size_t ws_size,
                              hipStream_t stream) {
    (void)in_sizes; (void)n_in; (void)out_size; (void)ws_size;
    const float* q  = (const float*)d_in[0];
    const float* k  = (const float*)d_in[1];
    const float* v  = (const float*)d_in[2];
    const unsigned char* mask = (const unsigned char*)d_in[3];
    const float* Wq = (const float*)d_in[4];
    const float* bq = (const float*)d_in[5];
    const float* Wk = (const float*)d_in[6];
    const float* bk = (const float*)d_in[7];
    const float* Wv = (const float*)d_in[8];
    const float* bv = (const float*)d_in[9];
    const float* Wo = (const float*)d_in[10];
    const float* bo = (const float*)d_in[11];
    float* out = (float*)d_out;

    u16* ws16 = (u16*)d_ws;
    const size_t M4 = (size_t)4 * 1024 * 1024;
    const size_t M1 = (size_t)1024 * 1024;
    u16* Qp  = ws16;            // [B,H,L,HD] bf16, 8 MiB
    u16* Kp  = ws16 + M4;       // [B,H,L,HD] 8 MiB
    u16* Vtp = ws16 + 2 * M4;   // [B,H,HD,L] (transposed) 8 MiB
    u16* AOb = ws16 + 3 * M4;   // [B,L,D] bf16, 8 MiB
    u16* Wqb = ws16 + 4 * M4;           // 2 MiB
    u16* Wkb = ws16 + 4 * M4 + M1;      // 2 MiB
    u16* Wvb = ws16 + 4 * M4 + 2 * M1;  // 2 MiB
    u16* Wob = ws16 + 4 * M4 + 3 * M1;  // 2 MiB

    conv_w<<<dim3(1024, 4), 256, 0, stream>>>(Wq, Wk, Wv, Wo, Wqb, Wkb, Wvb, Wob);
    qkv_gemm<<<dim3(32, 8, 3), 256, 0, stream>>>(q, k, v, Wqb, Wkb, Wvb,
                                                 bq, bk, bv, Qp, Kp, Vtp);
    attn_mfma<<<dim3(16, 32), 256, 0, stream>>>(Qp, Kp, Vtp, mask, AOb);
    out_gemm<<<dim3(32, 8), 256, 0, stream>>>(AOb, Wob, bo, out);
}

// Round 5
// 270.972 us; speedup vs baseline: 6.3262x; 1.1392x over previous
//
#include <hip/hip_runtime.h>

#define LSEQ 2048
#define DMODEL 1024
#define NHEAD 16
#define HDIM 64

typedef __attribute__((ext_vector_type(8))) short bf16x8;
typedef __attribute__((ext_vector_type(4))) float f32x4;
typedef unsigned int u32;
typedef unsigned short u16;

// cheap scalar fp32->bf16 (round-half-up; 2 VALU ops)
static __device__ __forceinline__ u16 f2bf(float x) {
    return (u16)((__builtin_bit_cast(u32, x) + 0x8000u) >> 16);
}

// packed pair: returns bf16(hi)<<16 | bf16(lo)
static __device__ __forceinline__ u32 f2bf_pk(float hi, float lo) {
    u32 a = __builtin_bit_cast(u32, hi) + 0x8000u;
    u32 b = __builtin_bit_cast(u32, lo) + 0x8000u;
#if __has_builtin(__builtin_amdgcn_perm)
    return __builtin_amdgcn_perm(a, b, 0x07060302u);  // {a.hi16, b.hi16}
#else
    return (a & 0xFFFF0000u) | (b >> 16);
#endif
}

static __device__ __forceinline__ float fast_exp2(float x) {
#if __has_builtin(__builtin_amdgcn_exp2f)
    return __builtin_amdgcn_exp2f(x);
#else
    return __expf(x * 0.6931471805599453f);
#endif
}

// async global->LDS, 16B/lane. LDS dest must be wave-uniform base + lane*16.
static __device__ __forceinline__ void gll16(const void* g, void* l) {
    __builtin_amdgcn_global_load_lds(
        (const __attribute__((address_space(1))) u32*)g,
        (__attribute__((address_space(3))) u32*)l, 16, 0, 0);
}

// ---------------------------------------------------------------------------
// Bulk fp32->bf16 conversion: z = 0..2 -> q,k,v (4M elems); z = 3..6 -> weights
// (1M elems, only first 1024 blocks active). Packed perm conversion.
// ---------------------------------------------------------------------------
__global__ __launch_bounds__(256) void conv_all(
    const float* __restrict__ q, const float* __restrict__ k, const float* __restrict__ v,
    const float* __restrict__ w0, const float* __restrict__ w1,
    const float* __restrict__ w2, const float* __restrict__ w3,
    u16* __restrict__ Qf, u16* __restrict__ Kf, u16* __restrict__ Vf,
    u16* __restrict__ o0, u16* __restrict__ o1, u16* __restrict__ o2,
    u16* __restrict__ o3) {
    const int z = blockIdx.y;
    const float* s; u16* d;
    if (z == 0)      { s = q;  d = Qf; }
    else if (z == 1) { s = k;  d = Kf; }
    else if (z == 2) { s = v;  d = Vf; }
    else if (z == 3) { s = w0; d = o0; }
    else if (z == 4) { s = w1; d = o1; }
    else if (z == 5) { s = w2; d = o2; }
    else             { s = w3; d = o3; }
    if (z >= 3 && blockIdx.x >= 1024) return;
    const int i = (blockIdx.x * 256 + threadIdx.x) * 4;
    float4 x = *(const float4*)(s + i);
    uint2 r;
    r.x = f2bf_pk(x.y, x.x);
    r.y = f2bf_pk(x.w, x.z);
    *(uint2*)(d + i) = r;
}

// ---------------------------------------------------------------------------
// m97-style MFMA GEMM: Y = X @ W^T + bias. X bf16 flat [M,1024] (gll16 both
// operands). 128x128 tile, BK=32, 256 thr, 4 waves 2x2, 4x4 MFMAs each.
// OUT_MODE 0: bf16 head-split [B,H,L,HD]. 1: fp32 flat [M,N].
//          2: bf16 head-split TRANSPOSED [B,H,HD,L] (for V).
// ---------------------------------------------------------------------------
template <int OUT_MODE>
__device__ __forceinline__ void mfma_gemm(const u16* __restrict__ Xb,
                                          const u16* __restrict__ Wb,
                                          const float* __restrict__ bias,
                                          void* __restrict__ Yv) {
    __shared__ alignas(16) u16 As[128 * 32];
    __shared__ alignas(16) u16 Bs[128 * 32];

    const int tid = threadIdx.x;
    const int wave = tid >> 6, lane = tid & 63;
    const int l16 = lane & 15, quad = lane >> 4;
    const int wm = (wave >> 1) * 64, wn = (wave & 1) * 64;
    const int m0 = blockIdx.x * 128, n0 = blockIdx.y * 128;

    f32x4 acc[4][4];
    #pragma unroll
    for (int i = 0; i < 4; ++i)
        #pragma unroll
        for (int j = 0; j < 4; ++j)
            #pragma unroll
            for (int r = 0; r < 4; ++r) acc[i][j][r] = 0.0f;

    for (int k0 = 0; k0 < DMODEL; k0 += 32) {
        __syncthreads();
        gll16(Xb + (size_t)(m0 + (tid >> 2)) * DMODEL + k0 + (tid & 3) * 8,
              As + tid * 8);
        gll16(Xb + (size_t)(m0 + 64 + (tid >> 2)) * DMODEL + k0 + (tid & 3) * 8,
              As + 2048 + tid * 8);
        gll16(Wb + (size_t)(n0 + (tid >> 2)) * DMODEL + k0 + (tid & 3) * 8,
              Bs + tid * 8);
        gll16(Wb + (size_t)(n0 + 64 + (tid >> 2)) * DMODEL + k0 + (tid & 3) * 8,
              Bs + 2048 + tid * 8);
        __syncthreads();

        bf16x8 af[4], bf[4];
        #pragma unroll
        for (int mb = 0; mb < 4; ++mb)
            af[mb] = *(const bf16x8*)(As + (wm + mb * 16 + l16) * 32 + quad * 8);
        #pragma unroll
        for (int nb = 0; nb < 4; ++nb)
            bf[nb] = *(const bf16x8*)(Bs + (wn + nb * 16 + l16) * 32 + quad * 8);
        #pragma unroll
        for (int mb = 0; mb < 4; ++mb)
            #pragma unroll
            for (int nb = 0; nb < 4; ++nb)
                acc[mb][nb] = __builtin_amdgcn_mfma_f32_16x16x32_bf16(
                    af[mb], bf[nb], acc[mb][nb], 0, 0, 0);
    }

    // Epilogue. C-layout: col = l16, row = quad*4 + r.
    #pragma unroll
    for (int nb = 0; nb < 4; ++nb) {
        const int n = n0 + wn + nb * 16 + l16;
        const float bn = bias[n];
        #pragma unroll
        for (int mb = 0; mb < 4; ++mb) {
            const int mb0 = m0 + wm + mb * 16 + quad * 4;
            if (OUT_MODE == 2) {
                u16* Y = (u16*)Yv;
                uint2 rr;
                rr.x = f2bf_pk(acc[mb][nb][1] + bn, acc[mb][nb][0] + bn);
                rr.y = f2bf_pk(acc[mb][nb][3] + bn, acc[mb][nb][2] + bn);
                const int bb = mb0 >> 11, l = mb0 & 2047;
                const int h = n >> 6, hd = n & 63;
                *(uint2*)(Y + ((size_t)((bb * NHEAD + h) * HDIM) + hd) * LSEQ + l) = rr;
            } else {
                #pragma unroll
                for (int r = 0; r < 4; ++r) {
                    const int m = mb0 + r;
                    const float val = acc[mb][nb][r] + bn;
                    if (OUT_MODE == 0) {
                        u16* Y = (u16*)Yv;
                        const int bb = m >> 11, l = m & 2047;
                        const int h = n >> 6, hd = n & 63;
                        Y[(((size_t)(bb * NHEAD + h) * LSEQ + l) * HDIM) + hd] = f2bf(val);
                    } else {
                        float* Y = (float*)Yv;
                        Y[(size_t)m * DMODEL + n] = val;
                    }
                }
            }
        }
    }
}

__global__ __launch_bounds__(256) void qkv_gemm(
    const u16* __restrict__ Qf, const u16* __restrict__ Kf, const u16* __restrict__ Vf,
    const u16* __restrict__ Wqb, const u16* __restrict__ Wkb, const u16* __restrict__ Wvb,
    const float* __restrict__ bq, const float* __restrict__ bk, const float* __restrict__ bv,
    u16* __restrict__ Qp, u16* __restrict__ Kp, u16* __restrict__ Vtp) {
    if (blockIdx.z == 0)      mfma_gemm<0>(Qf, Wqb, bq, (void*)Qp);
    else if (blockIdx.z == 1) mfma_gemm<0>(Kf, Wkb, bk, (void*)Kp);
    else                      mfma_gemm<2>(Vf, Wvb, bv, (void*)Vtp);
}

__global__ __launch_bounds__(256) void out_gemm(
    const u16* __restrict__ AOb, const u16* __restrict__ Wob,
    const float* __restrict__ bo, float* __restrict__ out) {
    mfma_gemm<1>(AOb, Wob, bo, (void*)out);
}

// ---------------------------------------------------------------------------
// MFMA flash attention v3. Block = 64 q of one (b,h), 4 waves x 16 q.
// KT=128 keys per iteration. K staged as 2 unpadded d-halves [2][128][32],
// V^T as 4 unpadded key-quarters [4][64][32] — both gll16-compatible AND
// conflict-free for b128 frag reads (window = (4*l16+quad)%8, uniform).
// Softmax in exp2 domain; row-max via DPP butterfly; row-sum/l via ones-MFMA.
// Grid (bh, qtile): linear id % 8 = bh % 8 -> all q-tiles of a bh share XCD.
// ---------------------------------------------------------------------------
#define KT 128
#define PSTR 136  // P row stride in u16 (16B-aligned, conflict-free reads)

__global__ __launch_bounds__(256, 3) void attn_mfma(
    const u16* __restrict__ Qp, const u16* __restrict__ Kp,
    const u16* __restrict__ Vtp, const unsigned char* __restrict__ mask,
    u16* __restrict__ AOb) {
    __shared__ alignas(16) u16 Ks[2 * 128 * 32];
    __shared__ alignas(16) u16 Vts[4 * 64 * 32];
    __shared__ alignas(16) u16 Ps[4][16 * PSTR];
    __shared__ float bias_s[KT];

    const int tid = threadIdx.x;
    const int wave = tid >> 6;
    const int lane = tid & 63;
    const int l16 = lane & 15;
    const int quad = lane >> 4;
    const int bh = blockIdx.x;            // swizzle: bh fast -> same XCD
    const int b = bh >> 4;
    const int h = bh & 15;
    const int q0w = blockIdx.y * 64 + wave * 16;

    const u16* Qg = Qp + ((size_t)bh * LSEQ + q0w) * HDIM;
    const u16* Kg = Kp + (size_t)bh * LSEQ * HDIM;
    const u16* Vtg = Vtp + (size_t)bh * HDIM * LSEQ;
    const unsigned char* mg = mask + (size_t)b * LSEQ;

    // Resident Q A-frags: A[m=l16][k=c*32+quad*8+j]
    bf16x8 qf[2];
    qf[0] = *(const bf16x8*)(Qg + (size_t)l16 * HDIM + quad * 8);
    qf[1] = *(const bf16x8*)(Qg + (size_t)l16 * HDIM + 32 + quad * 8);

    f32x4 o[4], ol;
    float m_r[4];
    #pragma unroll
    for (int nb = 0; nb < 4; ++nb)
        #pragma unroll
        for (int r = 0; r < 4; ++r) o[nb][r] = 0.0f;
    #pragma unroll
    for (int r = 0; r < 4; ++r) { ol[r] = 0.0f; m_r[r] = -1e30f; }

    union { bf16x8 v; u16 u[8]; } ones_u;
    #pragma unroll
    for (int j = 0; j < 8; ++j) ones_u.u[j] = 0x3F80;  // bf16 1.0
    const bf16x8 ones = ones_u.v;

    const float SC = 0.125f * 1.4426950408889634f;  // scale * log2(e)

    for (int kt = 0; kt < LSEQ / KT; ++kt) {
        const int k0 = kt * KT;
        float bias_v = 0.0f;
        if (tid < KT) bias_v = mg[k0 + tid] ? -1e30f : 0.0f;

        __syncthreads();  // prior iteration's Ks/Vts reads complete
        // K: 2 d-halves x 128 rows x 32 u16 (64B rows) -> 1024 chunks
        #pragma unroll
        for (int j = 0; j < 4; ++j) {
            const int cid = j * 256 + tid;
            const int h2 = cid >> 9, rem = cid & 511;
            const int row = rem >> 2, dc = rem & 3;
            gll16(Kg + (size_t)(k0 + row) * HDIM + h2 * 32 + dc * 8, Ks + cid * 8);
        }
        // V^T: 4 key-quarters x 64 d-rows x 32 u16 -> 1024 chunks
        #pragma unroll
        for (int j = 0; j < 4; ++j) {
            const int cid = j * 256 + tid;
            const int qc = cid >> 8, rem = cid & 255;
            const int d = rem >> 2, kc = rem & 3;
            gll16(Vtg + (size_t)d * LSEQ + k0 + qc * 32 + kc * 8, Vts + cid * 8);
        }
        if (tid < KT) bias_s[tid] = bias_v;
        __syncthreads();  // staging drained (compiler emits vmcnt(0))

        // ---- S = Q K^T (16q x 128 keys) ----
        f32x4 s[8];
        #pragma unroll
        for (int kb = 0; kb < 8; ++kb)
            #pragma unroll
            for (int r = 0; r < 4; ++r) s[kb][r] = 0.0f;
        #pragma unroll
        for (int c = 0; c < 2; ++c)
            #pragma unroll
            for (int kb = 0; kb < 8; ++kb) {
                bf16x8 kf = *(const bf16x8*)(Ks + c * 4096 + (kb * 16 + l16) * 32 + quad * 8);
                s[kb] = __builtin_amdgcn_mfma_f32_16x16x32_bf16(qf[c], kf, s[kb], 0, 0, 0);
            }
        // scale to log2 domain + mask bias (C-layout: row=quad*4+r, col=kb*16+l16)
        #pragma unroll
        for (int kb = 0; kb < 8; ++kb) {
            const float bb = bias_s[kb * 16 + l16];
            #pragma unroll
            for (int r = 0; r < 4; ++r) s[kb][r] = s[kb][r] * SC + bb;
        }

        // ---- online softmax (exp2 domain) ----
        u16* Pw = &Ps[wave][0];
        #pragma unroll
        for (int r = 0; r < 4; ++r) {
            float mx = s[0][r];
            #pragma unroll
            for (int kb = 1; kb < 8; ++kb) mx = fmaxf(mx, s[kb][r]);
            // 16-lane DPP butterfly (VALU pipe)
            int t;
            t = __builtin_amdgcn_update_dpp(0, __builtin_bit_cast(int, mx), 0x128, 0xf, 0xf, true);
            mx = fmaxf(mx, __builtin_bit_cast(float, t));
            t = __builtin_amdgcn_update_dpp(0, __builtin_bit_cast(int, mx), 0x124, 0xf, 0xf, true);
            mx = fmaxf(mx, __builtin_bit_cast(float, t));
            t = __builtin_amdgcn_update_dpp(0, __builtin_bit_cast(int, mx), 0x122, 0xf, 0xf, true);
            mx = fmaxf(mx, __builtin_bit_cast(float, t));
            t = __builtin_amdgcn_update_dpp(0, __builtin_bit_cast(int, mx), 0x121, 0xf, 0xf, true);
            mx = fmaxf(mx, __builtin_bit_cast(float, t));

            const float mnew = fmaxf(m_r[r], mx);
            const float alpha = fast_exp2(m_r[r] - mnew);
            m_r[r] = mnew;
            #pragma unroll
            for (int kb = 0; kb < 8; ++kb) s[kb][r] = fast_exp2(s[kb][r] - mnew);
            ol[r] *= alpha;
            #pragma unroll
            for (int nb = 0; nb < 4; ++nb) o[nb][r] *= alpha;
        }

        // ---- P: C-layout -> per-wave LDS -> A-layout ----
        #pragma unroll
        for (int kb = 0; kb < 8; ++kb)
            #pragma unroll
            for (int r = 0; r < 4; ++r)
                Pw[(quad * 4 + r) * PSTR + kb * 16 + l16] = f2bf(s[kb][r]);
        asm volatile("s_waitcnt lgkmcnt(0)" ::: "memory");

        bf16x8 pf[4];
        #pragma unroll
        for (int c = 0; c < 4; ++c)
            pf[c] = *(const bf16x8*)(Pw + l16 * PSTR + c * 32 + quad * 8);

        // ---- O += P V ; l += P . ones ----
        #pragma unroll
        for (int nb = 0; nb < 4; ++nb)
            #pragma unroll
            for (int c = 0; c < 4; ++c) {
                bf16x8 vf = *(const bf16x8*)(Vts + c * 2048 + (nb * 16 + l16) * 32 + quad * 8);
                o[nb] = __builtin_amdgcn_mfma_f32_16x16x32_bf16(pf[c], vf, o[nb], 0, 0, 0);
            }
        #pragma unroll
        for (int c = 0; c < 4; ++c)
            ol = __builtin_amdgcn_mfma_f32_16x16x32_bf16(pf[c], ones, ol, 0, 0, 0);
    }

    // Epilogue: O /= l, store bf16 to AOb [B, L, D] (concat heads)
    #pragma unroll
    for (int r = 0; r < 4; ++r) {
        const float inv = 1.0f / ol[r];
        const int row = q0w + quad * 4 + r;
        u16* dst = AOb + ((size_t)(b * LSEQ + row) * DMODEL) + h * HDIM;
        #pragma unroll
        for (int nb = 0; nb < 4; ++nb)
            dst[nb * 16 + l16] = f2bf(o[nb][r] * inv);
    }
}

extern "C" void kernel_launch(void* const* d_in, const int* in_sizes, int n_in,
                              void* d_out, int out_size, void* d_ws, size_t ws_size,
                              hipStream_t stream) {
    (void)in_sizes; (void)n_in; (void)out_size; (void)ws_size;
    const float* q  = (const float*)d_in[0];
    const float* k  = (const float*)d_in[1];
    const float* v  = (const float*)d_in[2];
    const unsigned char* mask = (const unsigned char*)d_in[3];
    const float* Wq = (const float*)d_in[4];
    const float* bq = (const float*)d_in[5];
    const float* Wk = (const float*)d_in[6];
    const float* bk = (const float*)d_in[7];
    const float* Wv = (const float*)d_in[8];
    const float* bv = (const float*)d_in[9];
    const float* Wo = (const float*)d_in[10];
    const float* bo = (const float*)d_in[11];
    float* out = (float*)d_out;

    u16* ws16 = (u16*)d_ws;
    const size_t M4 = (size_t)4 * 1024 * 1024;
    const size_t M1 = (size_t)1024 * 1024;
    u16* Qf  = ws16;            // bf16 flat [B*L, D], 8 MiB
    u16* Kf  = ws16 + M4;
    u16* Vf  = ws16 + 2 * M4;
    u16* Qp  = ws16 + 3 * M4;   // [B,H,L,HD]
    u16* Kp  = ws16 + 4 * M4;   // [B,H,L,HD]
    u16* Vtp = ws16 + 5 * M4;   // [B,H,HD,L]
    u16* AOb = ws16 + 6 * M4;   // [B,L,D]
    u16* Wqb = ws16 + 7 * M4;
    u16* Wkb = ws16 + 7 * M4 + M1;
    u16* Wvb = ws16 + 7 * M4 + 2 * M1;
    u16* Wob = ws16 + 7 * M4 + 3 * M1;

    conv_all<<<dim3(4096, 7), 256, 0, stream>>>(q, k, v, Wq, Wk, Wv, Wo,
                                                Qf, Kf, Vf, Wqb, Wkb, Wvb, Wob);
    qkv_gemm<<<dim3(32, 8, 3), 256, 0, stream>>>(Qf, Kf, Vf, Wqb, Wkb, Wvb,
                                                 bq, bk, bv, Qp, Kp, Vtp);
    attn_mfma<<<dim3(32, 32), 256, 0, stream>>>(Qp, Kp, Vtp, mask, AOb);
    out_gemm<<<dim3(32, 8), 256, 0, stream>>>(AOb, Wob, bo, out);
}

// Round 6
// 240.641 us; speedup vs baseline: 7.1235x; 1.1260x over previous
//
#include <hip/hip_runtime.h>

#define LSEQ 2048
#define DMODEL 1024
#define NHEAD 16
#define HDIM 64

typedef __attribute__((ext_vector_type(8))) short bf16x8;
typedef __attribute__((ext_vector_type(4))) float f32x4;
typedef __attribute__((ext_vector_type(16))) float f32x16;
typedef unsigned int u32;
typedef unsigned short u16;

static __device__ __forceinline__ u16 f2bf(float x) {
    return (u16)((__builtin_bit_cast(u32, x) + 0x8000u) >> 16);
}

// packed pair: returns bf16(hi)<<16 | bf16(lo)
static __device__ __forceinline__ u32 f2bf_pk(float hi, float lo) {
    u32 a = __builtin_bit_cast(u32, hi) + 0x8000u;
    u32 b = __builtin_bit_cast(u32, lo) + 0x8000u;
#if __has_builtin(__builtin_amdgcn_perm)
    return __builtin_amdgcn_perm(a, b, 0x07060302u);
#else
    return (a & 0xFFFF0000u) | (b >> 16);
#endif
}

static __device__ __forceinline__ float fast_exp2(float x) {
#if __has_builtin(__builtin_amdgcn_exp2f)
    return __builtin_amdgcn_exp2f(x);
#else
    return __expf(x * 0.6931471805599453f);
#endif
}

// async global->LDS, 16B/lane. LDS dest must be wave-uniform base + lane*16.
static __device__ __forceinline__ void gll16(const void* g, void* l) {
    __builtin_amdgcn_global_load_lds(
        (const __attribute__((address_space(1))) u32*)g,
        (__attribute__((address_space(3))) u32*)l, 16, 0, 0);
}

// ---------------------------------------------------------------------------
// Bulk fp32->bf16 conversion: z=0..2 -> q,k,v (4M elems); z=3..6 -> weights.
// ---------------------------------------------------------------------------
__global__ __launch_bounds__(256) void conv_all(
    const float* __restrict__ q, const float* __restrict__ k, const float* __restrict__ v,
    const float* __restrict__ w0, const float* __restrict__ w1,
    const float* __restrict__ w2, const float* __restrict__ w3,
    u16* __restrict__ Qf, u16* __restrict__ Kf, u16* __restrict__ Vf,
    u16* __restrict__ o0, u16* __restrict__ o1, u16* __restrict__ o2,
    u16* __restrict__ o3) {
    const int z = blockIdx.y;
    const float* s; u16* d;
    if (z == 0)      { s = q;  d = Qf; }
    else if (z == 1) { s = k;  d = Kf; }
    else if (z == 2) { s = v;  d = Vf; }
    else if (z == 3) { s = w0; d = o0; }
    else if (z == 4) { s = w1; d = o1; }
    else if (z == 5) { s = w2; d = o2; }
    else             { s = w3; d = o3; }
    if (z >= 3 && blockIdx.x >= 1024) return;
    const int i = (blockIdx.x * 256 + threadIdx.x) * 4;
    float4 x = *(const float4*)(s + i);
    uint2 r;
    r.x = f2bf_pk(x.y, x.x);
    r.y = f2bf_pk(x.w, x.z);
    *(uint2*)(d + i) = r;
}

// ---------------------------------------------------------------------------
// m97-style MFMA GEMM: Y = X @ W^T + bias, both operands bf16 via gll16.
// 128x128 tile, BK=32. OUT_MODE 0: bf16 [B,H,L,HD]; 1: fp32 flat;
// 2: bf16 transposed [B,H,HD,L] (for V).
// ---------------------------------------------------------------------------
template <int OUT_MODE>
__device__ __forceinline__ void mfma_gemm(const u16* __restrict__ Xb,
                                          const u16* __restrict__ Wb,
                                          const float* __restrict__ bias,
                                          void* __restrict__ Yv) {
    __shared__ alignas(16) u16 As[128 * 32];
    __shared__ alignas(16) u16 Bs[128 * 32];

    const int tid = threadIdx.x;
    const int wave = tid >> 6, lane = tid & 63;
    const int l16 = lane & 15, quad = lane >> 4;
    const int wm = (wave >> 1) * 64, wn = (wave & 1) * 64;
    const int m0 = blockIdx.x * 128, n0 = blockIdx.y * 128;

    f32x4 acc[4][4];
    #pragma unroll
    for (int i = 0; i < 4; ++i)
        #pragma unroll
        for (int j = 0; j < 4; ++j)
            #pragma unroll
            for (int r = 0; r < 4; ++r) acc[i][j][r] = 0.0f;

    for (int k0 = 0; k0 < DMODEL; k0 += 32) {
        __syncthreads();
        gll16(Xb + (size_t)(m0 + (tid >> 2)) * DMODEL + k0 + (tid & 3) * 8,
              As + tid * 8);
        gll16(Xb + (size_t)(m0 + 64 + (tid >> 2)) * DMODEL + k0 + (tid & 3) * 8,
              As + 2048 + tid * 8);
        gll16(Wb + (size_t)(n0 + (tid >> 2)) * DMODEL + k0 + (tid & 3) * 8,
              Bs + tid * 8);
        gll16(Wb + (size_t)(n0 + 64 + (tid >> 2)) * DMODEL + k0 + (tid & 3) * 8,
              Bs + 2048 + tid * 8);
        __syncthreads();

        bf16x8 af[4], bf[4];
        #pragma unroll
        for (int mb = 0; mb < 4; ++mb)
            af[mb] = *(const bf16x8*)(As + (wm + mb * 16 + l16) * 32 + quad * 8);
        #pragma unroll
        for (int nb = 0; nb < 4; ++nb)
            bf[nb] = *(const bf16x8*)(Bs + (wn + nb * 16 + l16) * 32 + quad * 8);
        #pragma unroll
        for (int mb = 0; mb < 4; ++mb)
            #pragma unroll
            for (int nb = 0; nb < 4; ++nb)
                acc[mb][nb] = __builtin_amdgcn_mfma_f32_16x16x32_bf16(
                    af[mb], bf[nb], acc[mb][nb], 0, 0, 0);
    }

    #pragma unroll
    for (int nb = 0; nb < 4; ++nb) {
        const int n = n0 + wn + nb * 16 + l16;
        const float bn = bias[n];
        #pragma unroll
        for (int mb = 0; mb < 4; ++mb) {
            const int mb0 = m0 + wm + mb * 16 + quad * 4;
            if (OUT_MODE == 2) {
                u16* Y = (u16*)Yv;
                uint2 rr;
                rr.x = f2bf_pk(acc[mb][nb][1] + bn, acc[mb][nb][0] + bn);
                rr.y = f2bf_pk(acc[mb][nb][3] + bn, acc[mb][nb][2] + bn);
                const int bb = mb0 >> 11, l = mb0 & 2047;
                const int h = n >> 6, hd = n & 63;
                *(uint2*)(Y + ((size_t)((bb * NHEAD + h) * HDIM) + hd) * LSEQ + l) = rr;
            } else {
                #pragma unroll
                for (int r = 0; r < 4; ++r) {
                    const int m = mb0 + r;
                    const float val = acc[mb][nb][r] + bn;
                    if (OUT_MODE == 0) {
                        u16* Y = (u16*)Yv;
                        const int bb = m >> 11, l = m & 2047;
                        const int h = n >> 6, hd = n & 63;
                        Y[(((size_t)(bb * NHEAD + h) * LSEQ + l) * HDIM) + hd] = f2bf(val);
                    } else {
                        float* Y = (float*)Yv;
                        Y[(size_t)m * DMODEL + n] = val;
                    }
                }
            }
        }
    }
}

__global__ __launch_bounds__(256) void qkv_gemm(
    const u16* __restrict__ Qf, const u16* __restrict__ Kf, const u16* __restrict__ Vf,
    const u16* __restrict__ Wqb, const u16* __restrict__ Wkb, const u16* __restrict__ Wvb,
    const float* __restrict__ bq, const float* __restrict__ bk, const float* __restrict__ bv,
    u16* __restrict__ Qp, u16* __restrict__ Kp, u16* __restrict__ Vtp) {
    if (blockIdx.z == 0)      mfma_gemm<0>(Qf, Wqb, bq, (void*)Qp);
    else if (blockIdx.z == 1) mfma_gemm<0>(Kf, Wkb, bk, (void*)Kp);
    else                      mfma_gemm<2>(Vf, Wvb, bv, (void*)Vtp);
}

__global__ __launch_bounds__(256) void out_gemm(
    const u16* __restrict__ AOb, const u16* __restrict__ Wob,
    const float* __restrict__ bo, float* __restrict__ out) {
    mfma_gemm<1>(AOb, Wob, bo, (void*)out);
}

// ---------------------------------------------------------------------------
// MFMA flash attention v4: 32x32x16 MFMAs, S^T/O^T operand-swap formulation.
// Block = 128 q of one (b,h); 4 waves x 32 q (lane&31 = q). KT=128 keys/iter.
// S^T = K.Q^T : A = K-frag (LDS, swizzled), B = Q-frag (registers).
// O^T = V^T.P^T : A = V^T-frag (LDS, swizzled), B = P^T built IN REGISTERS
// from S^T's C-layout via 2 shfl_xor(32) + selects per 16-key chunk.
// Per-lane scalar softmax state (m,l); double-buffered gll16 staging (64 KB).
// ---------------------------------------------------------------------------
#define KT 128

__global__ __launch_bounds__(256, 2) void attn_mfma(
    const u16* __restrict__ Qp, const u16* __restrict__ Kp,
    const u16* __restrict__ Vtp, const unsigned char* __restrict__ mask,
    u16* __restrict__ AOb) {
    __shared__ alignas(16) u16 smem[32768];  // 64 KB: K dbuf 2x16KB | V^T dbuf 2x16KB

    const int tid = threadIdx.x;
    const int wave = tid >> 6;
    const int lane = tid & 63;
    const int l32 = lane & 31;
    const int half = lane >> 5;
    const int bh = blockIdx.x;            // linear%8 = bh%8 -> per-bh XCD locality
    const int b = bh >> 4;
    const int h = bh & 15;
    const int q0 = blockIdx.y * 128;
    const int qw = q0 + wave * 32;

    const u16* Qg = Qp + ((size_t)bh * LSEQ + qw) * HDIM;
    const u16* Kg = Kp + (size_t)bh * LSEQ * HDIM;
    const u16* Vtg = Vtp + (size_t)bh * HDIM * LSEQ;
    const unsigned char* mg = mask + (size_t)b * LSEQ;

    // Q resident as B-frags: B[k=d][n=q]: lane q=l32, d = dc*16 + half*8 + j
    bf16x8 qf[4];
    #pragma unroll
    for (int dc = 0; dc < 4; ++dc)
        qf[dc] = *(const bf16x8*)(Qg + (size_t)l32 * HDIM + dc * 16 + half * 8);

    f32x16 o0 = {}, o1 = {};
    float m_l = -1e30f, l_l = 0.0f;
    const float SC = 0.125f * 1.4426950408889634f;  // scale * log2(e)

    // Staging: K tile [128 key][64 d], rows 8 chunks, phys = c ^ (key&7).
    //          V^T tile [64 d][128 key], rows 16 chunks, phys = c ^ (d&15).
    // gll16 dest = base + cid*16B (wave-uniform + lane*16 ok); swizzle via src.
    auto stage = [&](int ktile, int buf) {
        const int k0 = ktile * KT;
        u16* Kb = smem + buf * 8192;
        u16* Vb = smem + 16384 + buf * 8192;
        #pragma unroll
        for (int j = 0; j < 4; ++j) {
            const int cid = j * 256 + tid;
            const int key = cid >> 3, pc = cid & 7, c = pc ^ (key & 7);
            gll16(Kg + (size_t)(k0 + key) * HDIM + c * 8, Kb + cid * 8);
        }
        #pragma unroll
        for (int j = 0; j < 4; ++j) {
            const int cid = j * 256 + tid;
            const int d = cid >> 4, pc = cid & 15, c = pc ^ (d & 15);
            gll16(Vtg + (size_t)d * LSEQ + k0 + c * 8, Vb + cid * 8);
        }
    };

    stage(0, 0);

    for (int kt = 0; kt < LSEQ / KT; ++kt) {
        const int cur = kt & 1;
        const u16* Kb = smem + cur * 8192;
        const u16* Vb = smem + 16384 + cur * 8192;
        const int k0 = kt * KT;
        const int mb0 = mg[k0 + lane];
        const int mb1 = mg[k0 + 64 + lane];

        __syncthreads();  // staged buf[cur] complete; prior reads of it done
        if (kt + 1 < LSEQ / KT) stage(kt + 1, cur ^ 1);

        // ---- S^T = K . Q^T (4 key-blocks x 4 d-chunks) ----
        f32x16 st[4];
        #pragma unroll
        for (int kb = 0; kb < 4; ++kb) st[kb] = (f32x16)(0.0f);
        #pragma unroll
        for (int dc = 0; dc < 4; ++dc)
            #pragma unroll
            for (int kb = 0; kb < 4; ++kb) {
                const int key = kb * 32 + l32;
                const int phys = (dc * 2 + half) ^ (key & 7);
                bf16x8 kf = *(const bf16x8*)(Kb + key * 64 + phys * 8);
                st[kb] = __builtin_amdgcn_mfma_f32_32x32x16_bf16(kf, qf[dc], st[kb], 0, 0, 0);
            }

        // ---- mask (fast path: none) ----
        const unsigned long long anym = __ballot(mb0 | mb1);
        if (anym) {
            const float b0f = mb0 ? -1e30f : 0.0f;
            const float b1f = mb1 ? -1e30f : 0.0f;
            #pragma unroll
            for (int kb = 0; kb < 4; ++kb)
                #pragma unroll
                for (int r = 0; r < 16; ++r) {
                    const int key = kb * 32 + (r & 3) + 8 * (r >> 2) + 4 * half;
                    const float bv = __shfl((kb < 2) ? b0f : b1f, key & 63, 64);
                    st[kb][r] += bv;
                }
        }

        // ---- per-lane online softmax (lane owns one q; halves share state) --
        float mx = st[0][0];
        #pragma unroll
        for (int kb = 0; kb < 4; ++kb)
            #pragma unroll
            for (int r = 0; r < 16; ++r) mx = fmaxf(mx, st[kb][r]);
        mx = fmaxf(mx, __shfl_xor(mx, 32, 64));
        const float mnew = fmaxf(m_l, mx);
        const float msc = mnew * SC;
        const float alpha = fast_exp2(m_l * SC - msc);
        m_l = mnew;

        u32 pk[4][8];
        float rs = 0.0f;
        #pragma unroll
        for (int kb = 0; kb < 4; ++kb)
            #pragma unroll
            for (int w = 0; w < 8; ++w) {
                const float plo = fast_exp2(st[kb][2 * w] * SC - msc);
                const float phi = fast_exp2(st[kb][2 * w + 1] * SC - msc);
                rs += plo + phi;
                pk[kb][w] = f2bf_pk(phi, plo);
            }
        rs += __shfl_xor(rs, 32, 64);
        l_l = l_l * alpha + rs;
        #pragma unroll
        for (int r = 0; r < 16; ++r) { o0[r] *= alpha; o1[r] *= alpha; }

        // ---- O^T += V^T . P^T (8 key-chunks of 16) ----
        #pragma unroll
        for (int c = 0; c < 8; ++c) {
            const int kb = c >> 1, wb = 4 * (c & 1);
            const u32 ta = half ? pk[kb][wb] : pk[kb][wb + 2];
            const u32 tb = half ? pk[kb][wb + 1] : pk[kb][wb + 3];
            const u32 xa = __shfl_xor((int)ta, 32, 64);
            const u32 xb = __shfl_xor((int)tb, 32, 64);
            u32 w4[4];
            w4[0] = half ? xa : pk[kb][wb];
            w4[1] = half ? xb : pk[kb][wb + 1];
            w4[2] = half ? pk[kb][wb + 2] : xa;
            w4[3] = half ? pk[kb][wb + 3] : xb;
            bf16x8 pb = __builtin_bit_cast(bf16x8, *(uint4*)w4);
            {
                const int d = l32;                       // nb = 0
                const int phys = (c * 2 + half) ^ (d & 15);
                bf16x8 va = *(const bf16x8*)(Vb + d * 128 + phys * 8);
                o0 = __builtin_amdgcn_mfma_f32_32x32x16_bf16(va, pb, o0, 0, 0, 0);
            }
            {
                const int d = 32 + l32;                  // nb = 1
                const int phys = (c * 2 + half) ^ (d & 15);
                bf16x8 va = *(const bf16x8*)(Vb + d * 128 + phys * 8);
                o1 = __builtin_amdgcn_mfma_f32_32x32x16_bf16(va, pb, o1, 0, 0, 0);
            }
        }
    }

    // ---- Epilogue: O^T/l -> LDS transpose [q][d] (stride 72) -> coalesced ---
    const float inv = 1.0f / l_l;
    __syncthreads();  // all compute reads done before overwrite
    u16* T = smem;
    #pragma unroll
    for (int nb = 0; nb < 2; ++nb)
        #pragma unroll
        for (int rp = 0; rp < 8; ++rp) {
            const int r = rp * 2;
            const int d = nb * 32 + (r & 3) + 8 * (r >> 2) + 4 * half;
            const float vlo = (nb ? o1[r] : o0[r]) * inv;
            const float vhi = (nb ? o1[r + 1] : o0[r + 1]) * inv;
            *(u32*)(T + (wave * 32 + l32) * 72 + d) = f2bf_pk(vhi, vlo);
        }
    __syncthreads();
    #pragma unroll
    for (int i = 0; i < 4; ++i) {
        const int cid = i * 256 + tid;
        const int row = cid >> 3, ch = cid & 7;
        bf16x8 val = *(const bf16x8*)(T + row * 72 + ch * 8);
        *(bf16x8*)(AOb + ((size_t)(b * LSEQ + q0 + row) * DMODEL) + h * HDIM + ch * 8) = val;
    }
}

extern "C" void kernel_launch(void* const* d_in, const int* in_sizes, int n_in,
                              void* d_out, int out_size, void* d_ws, size_t ws_size,
                              hipStream_t stream) {
    (void)in_sizes; (void)n_in; (void)out_size; (void)ws_size;
    const float* q  = (const float*)d_in[0];
    const float* k  = (const float*)d_in[1];
    const float* v  = (const float*)d_in[2];
    const unsigned char* mask = (const unsigned char*)d_in[3];
    const float* Wq = (const float*)d_in[4];
    const float* bq = (const float*)d_in[5];
    const float* Wk = (const float*)d_in[6];
    const float* bk = (const float*)d_in[7];
    const float* Wv = (const float*)d_in[8];
    const float* bv = (const float*)d_in[9];
    const float* Wo = (const float*)d_in[10];
    const float* bo = (const float*)d_in[11];
    float* out = (float*)d_out;

    u16* ws16 = (u16*)d_ws;
    const size_t M4 = (size_t)4 * 1024 * 1024;
    const size_t M1 = (size_t)1024 * 1024;
    u16* Qf  = ws16;            // bf16 flat [B*L, D]
    u16* Kf  = ws16 + M4;
    u16* Vf  = ws16 + 2 * M4;
    u16* Qp  = ws16 + 3 * M4;   // [B,H,L,HD]
    u16* Kp  = ws16 + 4 * M4;   // [B,H,L,HD]
    u16* Vtp = ws16 + 5 * M4;   // [B,H,HD,L]
    u16* AOb = ws16 + 6 * M4;   // [B,L,D]
    u16* Wqb = ws16 + 7 * M4;
    u16* Wkb = ws16 + 7 * M4 + M1;
    u16* Wvb = ws16 + 7 * M4 + 2 * M1;
    u16* Wob = ws16 + 7 * M4 + 3 * M1;

    conv_all<<<dim3(4096, 7), 256, 0, stream>>>(q, k, v, Wq, Wk, Wv, Wo,
                                                Qf, Kf, Vf, Wqb, Wkb, Wvb, Wob);
    qkv_gemm<<<dim3(32, 8, 3), 256, 0, stream>>>(Qf, Kf, Vf, Wqb, Wkb, Wvb,
                                                 bq, bk, bv, Qp, Kp, Vtp);
    attn_mfma<<<dim3(32, 16), 256, 0, stream>>>(Qp, Kp, Vtp, mask, AOb);
    out_gemm<<<dim3(32, 8), 256, 0, stream>>>(AOb, Wob, bo, out);
}